// Round 1
// baseline (1292.240 us; speedup 1.0000x reference)
//
#include <hip/hip_runtime.h>
#include <math.h>

#define C_DIM 512
#define N_DIM 4096
#define D_DIM 64
#define CN (C_DIM * N_DIM)
#define NN_TOT ((long long)N_DIM * N_DIM)

// ---------------------------------------------------------------------------
// Generic projection / MLP GEMM:
//   Out[o*N + n] = post( mask[n] * sum_c W[o*K+c] * X[c*N+n] + bias[o] )
// maskMode: 0 = none, 1 = raw mask, 2 = binarized (mask > 0.8)
// post: optional *0.125 scale (Q), optional relu (MLP1)
// 64x64 tile, K-tile 16, 256 threads, 4x4 microtile.
// ---------------------------------------------------------------------------
__global__ __launch_bounds__(256) void proj_gemm(
    const float* __restrict__ W, const float* __restrict__ bias,
    const float* __restrict__ X, const float* __restrict__ mask,
    float* __restrict__ Out, int K, int maskMode, int doRelu, int doScale)
{
    __shared__ float As[16][65];  // [k][m]
    __shared__ float Bs[16][65];  // [k][n]
    const int tid = threadIdx.x;
    const int m0 = blockIdx.y * 64, n0 = blockIdx.x * 64;
    const int ty = tid >> 4, tx = tid & 15;
    float acc[4][4] = {};

    for (int k0 = 0; k0 < K; k0 += 16) {
        {   // W tile: 64 rows x 16 k (transpose into LDS)
            int mm = tid >> 2, kq = (tid & 3) * 4;
            const float4 w4 = *(const float4*)&W[(size_t)(m0 + mm) * K + k0 + kq];
            As[kq + 0][mm] = w4.x; As[kq + 1][mm] = w4.y;
            As[kq + 2][mm] = w4.z; As[kq + 3][mm] = w4.w;
        }
        {   // X tile: 16 k x 64 n (direct)
            int kk = tid >> 4, nq = (tid & 15) * 4;
            *(float4*)&Bs[kk][nq] = *(const float4*)&X[(size_t)(k0 + kk) * N_DIM + n0 + nq];
        }
        __syncthreads();
        #pragma unroll
        for (int kk = 0; kk < 16; ++kk) {
            float a[4], b[4];
            #pragma unroll
            for (int r = 0; r < 4; ++r) a[r] = As[kk][ty * 4 + r];
            #pragma unroll
            for (int c = 0; c < 4; ++c) b[c] = Bs[kk][tx * 4 + c];
            #pragma unroll
            for (int r = 0; r < 4; ++r)
                #pragma unroll
                for (int c = 0; c < 4; ++c)
                    acc[r][c] = fmaf(a[r], b[c], acc[r][c]);
        }
        __syncthreads();
    }

    float mk[4];
    #pragma unroll
    for (int c = 0; c < 4; ++c) {
        int n = n0 + tx * 4 + c;
        mk[c] = (maskMode == 0) ? 1.0f
              : (maskMode == 1) ? mask[n]
                                : (mask[n] > 0.8f ? 1.0f : 0.0f);
    }
    #pragma unroll
    for (int r = 0; r < 4; ++r) {
        float bo = bias[m0 + ty * 4 + r];
        float vals[4];
        #pragma unroll
        for (int c = 0; c < 4; ++c) {
            float v = acc[r][c] * mk[c] + bo;
            if (doScale) v *= 0.125f;
            if (doRelu)  v = fmaxf(v, 0.0f);
            vals[c] = v;
        }
        float4 o = make_float4(vals[0], vals[1], vals[2], vals[3]);
        *(float4*)&Out[(size_t)(m0 + ty * 4 + r) * N_DIM + n0 + tx * 4] = o;
    }
}

// ---------------------------------------------------------------------------
// attn[i*N + j] = sum_t Q[t*N+i] * K[t*N+j]   (Q,K stored [D=64][N])
// Fused: per-block partial max / min / sum of the tile -> part[]
// One K-pass (D=64 fits in LDS). 64x64 tile per block, grid 64x64.
// ---------------------------------------------------------------------------
__global__ __launch_bounds__(256) void attn_gemm(
    const float* __restrict__ Q, const float* __restrict__ Km,
    float* __restrict__ attn, float* __restrict__ part)
{
    __shared__ float Qs[64][65];
    __shared__ float Ks[64][65];
    const int tid = threadIdx.x;
    const int m0 = blockIdx.y * 64, n0 = blockIdx.x * 64;

    #pragma unroll
    for (int l = 0; l < 4; ++l) {
        int id = tid + l * 256;
        int kk = id >> 4, cq = (id & 15) * 4;
        *(float4*)&Qs[kk][cq] = *(const float4*)&Q[(size_t)kk * N_DIM + m0 + cq];
        *(float4*)&Ks[kk][cq] = *(const float4*)&Km[(size_t)kk * N_DIM + n0 + cq];
    }
    __syncthreads();

    const int ty = tid >> 4, tx = tid & 15;
    float acc[4][4] = {};
    #pragma unroll 16
    for (int kk = 0; kk < 64; ++kk) {
        float a[4], b[4];
        #pragma unroll
        for (int r = 0; r < 4; ++r) a[r] = Qs[kk][ty * 4 + r];
        #pragma unroll
        for (int c = 0; c < 4; ++c) b[c] = Ks[kk][tx * 4 + c];
        #pragma unroll
        for (int r = 0; r < 4; ++r)
            #pragma unroll
            for (int c = 0; c < 4; ++c)
                acc[r][c] = fmaf(a[r], b[c], acc[r][c]);
    }

    float lmax = -3.4e38f, lmin = 3.4e38f, lsum = 0.0f;
    #pragma unroll
    for (int r = 0; r < 4; ++r) {
        float4 o = make_float4(acc[r][0], acc[r][1], acc[r][2], acc[r][3]);
        *(float4*)&attn[(size_t)(m0 + ty * 4 + r) * N_DIM + n0 + tx * 4] = o;
        #pragma unroll
        for (int c = 0; c < 4; ++c) {
            float v = acc[r][c];
            lmax = fmaxf(lmax, v); lmin = fminf(lmin, v); lsum += v;
        }
    }

    __shared__ float red[256];
    int bid = blockIdx.y * gridDim.x + blockIdx.x;
    red[tid] = lmax; __syncthreads();
    for (int s = 128; s > 0; s >>= 1) { if (tid < s) red[tid] = fmaxf(red[tid], red[tid + s]); __syncthreads(); }
    if (tid == 0) part[bid] = red[0];
    __syncthreads();
    red[tid] = lmin; __syncthreads();
    for (int s = 128; s > 0; s >>= 1) { if (tid < s) red[tid] = fminf(red[tid], red[tid + s]); __syncthreads(); }
    if (tid == 0) part[4096 + bid] = red[0];
    __syncthreads();
    red[tid] = lsum; __syncthreads();
    for (int s = 128; s > 0; s >>= 1) { if (tid < s) red[tid] += red[tid + s]; __syncthreads(); }
    if (tid == 0) part[8192 + bid] = red[0];
}

// thr = 0.5 * ((useMax ? gmax : gmin) + gmean)  -> stats[0]
__global__ __launch_bounds__(256) void attn_stats_fin(
    const float* __restrict__ part, float* __restrict__ stats, int useMax)
{
    __shared__ float rmax[256], rmin[256];
    __shared__ double rsum[256];
    int tid = threadIdx.x;
    float m1 = -3.4e38f, m2 = 3.4e38f; double s = 0.0;
    for (int i = tid; i < 4096; i += 256) {
        m1 = fmaxf(m1, part[i]);
        m2 = fminf(m2, part[4096 + i]);
        s += (double)part[8192 + i];
    }
    rmax[tid] = m1; rmin[tid] = m2; rsum[tid] = s;
    __syncthreads();
    for (int st = 128; st > 0; st >>= 1) {
        if (tid < st) {
            rmax[tid] = fmaxf(rmax[tid], rmax[tid + st]);
            rmin[tid] = fminf(rmin[tid], rmin[tid + st]);
            rsum[tid] += rsum[tid + st];
        }
        __syncthreads();
    }
    if (tid == 0) {
        float stat = useMax ? rmax[0] : rmin[0];
        float mean = (float)(rsum[0] / (double)NN_TOT);
        stats[0] = 0.5f * (stat + mean);
    }
}

// In-place masked softmax per row. One block per row (4096 floats).
__global__ __launch_bounds__(256) void softmax_rows(
    float* __restrict__ attn, const float* __restrict__ stats)
{
    const float thr = stats[0];
    const int tid = threadIdx.x;
    float* row = attn + (size_t)blockIdx.x * N_DIM;
    float v[16];
    float lmax = -3.4e38f;
    #pragma unroll
    for (int k = 0; k < 16; ++k) {
        float a = row[tid + k * 256];
        a = (a < thr) ? -999.0f : a;
        v[k] = a;
        lmax = fmaxf(lmax, a);
    }
    __shared__ float red[256];
    red[tid] = lmax; __syncthreads();
    for (int s = 128; s > 0; s >>= 1) { if (tid < s) red[tid] = fmaxf(red[tid], red[tid + s]); __syncthreads(); }
    float m = red[0];
    __syncthreads();
    float lsum = 0.0f;
    #pragma unroll
    for (int k = 0; k < 16; ++k) { v[k] = __expf(v[k] - m); lsum += v[k]; }
    red[tid] = lsum; __syncthreads();
    for (int s = 128; s > 0; s >>= 1) { if (tid < s) red[tid] += red[tid + s]; __syncthreads(); }
    float inv = 1.0f / red[0];
    #pragma unroll
    for (int k = 0; k < 16; ++k) row[tid + k * 256] = v[k] * inv;
}

// ---------------------------------------------------------------------------
// out[c*N + i] = sum_j V[c*N + j] * P[i*N + j]   (both contiguous along j)
// M=512, N=4096, K=4096. 64x64 tile, K-tile 32.
// ---------------------------------------------------------------------------
__global__ __launch_bounds__(256) void gemm_vp(
    const float* __restrict__ V, const float* __restrict__ P, float* __restrict__ Out)
{
    __shared__ float As[32][65];  // [j][c]
    __shared__ float Bs[32][65];  // [j][i]
    const int tid = threadIdx.x;
    const int m0 = blockIdx.y * 64, n0 = blockIdx.x * 64;
    const int ty = tid >> 4, tx = tid & 15;
    float acc[4][4] = {};

    for (int k0 = 0; k0 < N_DIM; k0 += 32) {
        #pragma unroll
        for (int l = 0; l < 2; ++l) {
            int id = tid + l * 256;
            int row = id >> 3, kq = (id & 7) * 4;
            float4 a4 = *(const float4*)&V[(size_t)(m0 + row) * N_DIM + k0 + kq];
            As[kq + 0][row] = a4.x; As[kq + 1][row] = a4.y;
            As[kq + 2][row] = a4.z; As[kq + 3][row] = a4.w;
            float4 b4 = *(const float4*)&P[(size_t)(n0 + row) * N_DIM + k0 + kq];
            Bs[kq + 0][row] = b4.x; Bs[kq + 1][row] = b4.y;
            Bs[kq + 2][row] = b4.z; Bs[kq + 3][row] = b4.w;
        }
        __syncthreads();
        #pragma unroll
        for (int kk = 0; kk < 32; ++kk) {
            float a[4], b[4];
            #pragma unroll
            for (int r = 0; r < 4; ++r) a[r] = As[kk][ty * 4 + r];
            #pragma unroll
            for (int c = 0; c < 4; ++c) b[c] = Bs[kk][tx * 4 + c];
            #pragma unroll
            for (int r = 0; r < 4; ++r)
                #pragma unroll
                for (int c = 0; c < 4; ++c)
                    acc[r][c] = fmaf(a[r], b[c], acc[r][c]);
        }
        __syncthreads();
    }
    #pragma unroll
    for (int r = 0; r < 4; ++r) {
        float4 o = make_float4(acc[r][0], acc[r][1], acc[r][2], acc[r][3]);
        *(float4*)&Out[(size_t)(m0 + ty * 4 + r) * N_DIM + n0 + tx * 4] = o;
    }
}

// LayerNorm global stats over C*N elements.
__global__ __launch_bounds__(256) void ln_partial(
    const float* __restrict__ X, float* __restrict__ part)
{
    __shared__ float rs[256], rq[256];
    int tid = threadIdx.x;
    size_t base = (size_t)blockIdx.x * 2048;
    float s = 0.0f, q = 0.0f;
    #pragma unroll
    for (int k = 0; k < 8; ++k) {
        float v = X[base + tid + k * 256];
        s += v; q = fmaf(v, v, q);
    }
    rs[tid] = s; rq[tid] = q; __syncthreads();
    for (int st = 128; st > 0; st >>= 1) {
        if (tid < st) { rs[tid] += rs[tid + st]; rq[tid] += rq[tid + st]; }
        __syncthreads();
    }
    if (tid == 0) { part[blockIdx.x] = rs[0]; part[1024 + blockIdx.x] = rq[0]; }
}

__global__ __launch_bounds__(256) void ln_fin(
    const float* __restrict__ part, float* __restrict__ stats)
{
    __shared__ double rs[256], rq[256];
    int tid = threadIdx.x;
    double s = 0.0, q = 0.0;
    for (int i = tid; i < 1024; i += 256) { s += part[i]; q += part[1024 + i]; }
    rs[tid] = s; rq[tid] = q; __syncthreads();
    for (int st = 128; st > 0; st >>= 1) {
        if (tid < st) { rs[tid] += rs[tid + st]; rq[tid] += rq[tid + st]; }
        __syncthreads();
    }
    if (tid == 0) {
        double mu = rs[0] / (double)CN;
        double var = rq[0] / (double)CN - mu * mu;
        stats[1] = (float)mu;
        stats[2] = (float)(1.0 / sqrt(var + 1e-5));
    }
}

// normed = (H2-mu)*rs*gamma + beta ; out = normed*m + resid*(1-m)
__global__ __launch_bounds__(256) void gate_write(
    const float* __restrict__ H2, const float* __restrict__ stats,
    const float* __restrict__ gamma, const float* __restrict__ beta,
    const float* __restrict__ resid, const float* __restrict__ mask,
    float* __restrict__ out, int binarize)
{
    size_t idx = (size_t)blockIdx.x * 256 + threadIdx.x;
    int n = (int)(idx & (N_DIM - 1));
    float mu = stats[1], rs = stats[2];
    float normed = (H2[idx] - mu) * rs * gamma[idx] + beta[idx];
    float mv = mask[n];
    if (binarize) mv = (mv > 0.8f) ? 1.0f : 0.0f;
    out[idx] = normed * mv + resid[idx] * (1.0f - mv);
}

// ---------------------------------------------------------------------------
extern "C" void kernel_launch(void* const* d_in, const int* in_sizes, int n_in,
                              void* d_out, int out_size, void* d_ws, size_t ws_size,
                              hipStream_t stream)
{
    const float* x     = (const float*)d_in[0];
    const float* y     = (const float*)d_in[1];
    const float* s_m   = (const float*)d_in[2];
    const float* q_m   = (const float*)d_in[3];
    const float* Wq    = (const float*)d_in[4];
    const float* bq    = (const float*)d_in[5];
    const float* Wk    = (const float*)d_in[6];
    const float* bk    = (const float*)d_in[7];
    const float* Wv    = (const float*)d_in[8];
    const float* bv    = (const float*)d_in[9];
    const float* W1    = (const float*)d_in[10];
    const float* b1    = (const float*)d_in[11];
    const float* W2    = (const float*)d_in[12];
    const float* b2    = (const float*)d_in[13];
    const float* gamma = (const float*)d_in[14];
    const float* beta  = (const float*)d_in[15];
    float* out = (float*)d_out;

    float* ws   = (float*)d_ws;
    float* Qb   = ws;                    // 262144  ([64][4096])
    float* Kb   = Qb + 262144;           // 262144
    float* Vb   = Kb + 262144;           // 2097152 ([512][4096])
    float* ATT  = Vb + 2097152;          // 16777216 ([4096][4096])
    float* O1   = ATT + 16777216;        // 2097152
    float* H1   = O1 + 2097152;          // 2097152
    float* H2   = H1 + 2097152;          // 2097152
    float* PART = H2 + 2097152;          // 12288
    float* STATS= PART + 12288;          // 16

    for (int br = 0; br < 2; ++br) {
        const float* qin    = (br == 0) ? x   : y;
        const float* qmask  = (br == 0) ? s_m : q_m;
        int          qmode  = (br == 0) ? 1 : 2;
        const float* kvin   = (br == 0) ? y   : x;
        const float* kvmask = (br == 0) ? q_m : nullptr;
        int          kvmode = (br == 0) ? 2 : 0;

        proj_gemm<<<dim3(64, 1), 256, 0, stream>>>(Wq, bq, qin, qmask, Qb, 512, qmode, 0, 1);
        proj_gemm<<<dim3(64, 1), 256, 0, stream>>>(Wk, bk, kvin, kvmask, Kb, 512, kvmode, 0, 0);
        proj_gemm<<<dim3(64, 8), 256, 0, stream>>>(Wv, bv, kvin, kvmask, Vb, 512, kvmode, 0, 0);
        attn_gemm<<<dim3(64, 64), 256, 0, stream>>>(Qb, Kb, ATT, PART);
        attn_stats_fin<<<1, 256, 0, stream>>>(PART, STATS, (br == 0) ? 1 : 0);
        softmax_rows<<<4096, 256, 0, stream>>>(ATT, STATS);
        gemm_vp<<<dim3(64, 8), 256, 0, stream>>>(Vb, ATT, O1);
        proj_gemm<<<dim3(64, 8), 256, 0, stream>>>(W1, b1, O1, nullptr, H1, 512, 0, 1, 0);
        proj_gemm<<<dim3(64, 8), 256, 0, stream>>>(W2, b2, H1, nullptr, H2, 512, 0, 0, 0);
        ln_partial<<<1024, 256, 0, stream>>>(H2, PART);
        ln_fin<<<1, 256, 0, stream>>>(PART, STATS);
        gate_write<<<8192, 256, 0, stream>>>(H2, STATS, gamma, beta,
                                             (br == 0) ? x : y,
                                             (br == 0) ? s_m : q_m,
                                             out + (size_t)br * CN,
                                             (br == 0) ? 0 : 1);
    }
}

// Round 2
// 450.186 us; speedup vs baseline: 2.8705x; 2.8705x over previous
//
#include <hip/hip_runtime.h>
#include <math.h>

#define C_DIM 512
#define N_DIM 4096
#define CN (C_DIM * N_DIM)
#define NN_TOT ((long long)N_DIM * N_DIM)

typedef __attribute__((ext_vector_type(4))) float f32x4;
typedef __attribute__((ext_vector_type(8))) short short8;

__device__ __forceinline__ ushort f2bf(float f) {
    unsigned u = __float_as_uint(f);
    unsigned r = u + 0x7FFFu + ((u >> 16) & 1u);
    return (ushort)(r >> 16);
}

__device__ __forceinline__ void gload16(const void* g, void* l) {
    __builtin_amdgcn_global_load_lds(
        (const __attribute__((address_space(1))) void*)g,
        (__attribute__((address_space(3))) void*)l, 16, 0, 0);
}

// ---------------------------------------------------------------------------
// Transpose + convert: X f32 [R][NC] -> XT bf16 [NC][R]
// ---------------------------------------------------------------------------
__global__ __launch_bounds__(256) void tconv64(
    const float* __restrict__ X, ushort* __restrict__ XT, int R, int NC)
{
    __shared__ float t[64][65];
    const int c0 = blockIdx.x * 64;   // col offset in X (NC dim)
    const int r0 = blockIdx.y * 64;   // row offset in X (R dim)
    const int ty = threadIdx.x >> 4, tx = threadIdx.x & 15;
    #pragma unroll
    for (int i = 0; i < 4; ++i) {
        int r = ty + i * 16;
        float4 v = *(const float4*)&X[(size_t)(r0 + r) * NC + c0 + tx * 4];
        t[r][tx * 4 + 0] = v.x; t[r][tx * 4 + 1] = v.y;
        t[r][tx * 4 + 2] = v.z; t[r][tx * 4 + 3] = v.w;
    }
    __syncthreads();
    #pragma unroll
    for (int i = 0; i < 4; ++i) {
        int nn = ty + i * 16;
        ushort4 o;
        o.x = f2bf(t[tx * 4 + 0][nn]); o.y = f2bf(t[tx * 4 + 1][nn]);
        o.z = f2bf(t[tx * 4 + 2][nn]); o.w = f2bf(t[tx * 4 + 3][nn]);
        *(ushort4*)&XT[(size_t)(c0 + nn) * R + r0 + tx * 4] = o;
    }
}

// straight f32 -> bf16
__global__ __launch_bounds__(256) void cvtw(
    const float* __restrict__ in, ushort* __restrict__ out, int n)
{
    int i = (blockIdx.x * 256 + threadIdx.x) * 4;
    if (i < n) {
        float4 v = *(const float4*)&in[i];
        ushort4 o = { f2bf(v.x), f2bf(v.y), f2bf(v.z), f2bf(v.w) };
        *(ushort4*)&out[i] = o;
    }
}

// ---------------------------------------------------------------------------
// bf16 MFMA NT GEMM: Out[m][n] = sum_k A[m][k] * B[n][k]
// A [M][K] bf16, B [N][K] bf16, K = lda = ldb. 128x128 tile, 4 waves (2x2),
// BK=32, double-buffered LDS via global_load_lds width 16.
// If gridDim.z > 1: writes f32 partials (split-K), no epilogue ops.
// ---------------------------------------------------------------------------
__global__ __launch_bounds__(256) void mfma_nt(
    const ushort* __restrict__ A, const ushort* __restrict__ B,
    void* __restrict__ Out, int M, int N, int K, int kLen,
    const float* __restrict__ bias, int biasMode,   // 0 none, 1 per-row(m), 2 per-col(n)
    const float* __restrict__ mask, int maskMode,   // 0 none, 1 raw, 2 binarize (per col n)
    int doRelu, int outBf16)
{
    __shared__ ushort As[2][128 * 32];
    __shared__ ushort Bs[2][128 * 32];
    const int tid  = threadIdx.x;
    const int lane = tid & 63;
    const int wid  = tid >> 6;
    const int m0 = blockIdx.y * 128, n0 = blockIdx.x * 128;
    const int wr = (wid >> 1) * 64, wc = (wid & 1) * 64;
    const int kOff = blockIdx.z * kLen;

    // staging: wave w covers rows 16*(2w)..16*(2w+1)+15; lane -> row lane>>2, k (lane&3)*8
    const int srow  = wid * 32 + (lane >> 2);
    const int skoff = (lane & 3) * 8;
    const ushort* pA = A + (size_t)(m0 + srow) * K + kOff + skoff;
    const ushort* pB = B + (size_t)(n0 + srow) * K + kOff + skoff;

    auto stage = [&](int buf, int t) {
        const ushort* a = pA + (size_t)t * 32;
        const ushort* b = pB + (size_t)t * 32;
        gload16(a,                  &As[buf][(wid * 2 + 0) * 512]);
        gload16(a + (size_t)16 * K, &As[buf][(wid * 2 + 1) * 512]);
        gload16(b,                  &Bs[buf][(wid * 2 + 0) * 512]);
        gload16(b + (size_t)16 * K, &Bs[buf][(wid * 2 + 1) * 512]);
    };

    f32x4 acc[4][4] = {};
    const int fr = lane & 15;
    const int k8 = (lane >> 4) * 8;
    const int nt = kLen / 32;

    stage(0, 0);
    asm volatile("s_waitcnt vmcnt(0)" ::: "memory");
    __syncthreads();
    int cur = 0;
    for (int t = 0; t < nt; ++t) {
        if (t + 1 < nt) stage(cur ^ 1, t + 1);
        short8 af[4], bf[4];
        #pragma unroll
        for (int mr = 0; mr < 4; ++mr)
            af[mr] = *(const short8*)&As[cur][(wr + mr * 16 + fr) * 32 + k8];
        #pragma unroll
        for (int nc = 0; nc < 4; ++nc)
            bf[nc] = *(const short8*)&Bs[cur][(wc + nc * 16 + fr) * 32 + k8];
        #pragma unroll
        for (int mr = 0; mr < 4; ++mr)
            #pragma unroll
            for (int nc = 0; nc < 4; ++nc)
                acc[mr][nc] = __builtin_amdgcn_mfma_f32_16x16x32_bf16(
                    af[mr], bf[nc], acc[mr][nc], 0, 0, 0);
        asm volatile("s_waitcnt vmcnt(0)" ::: "memory");
        __syncthreads();
        cur ^= 1;
    }

    const int orow = (lane >> 4) * 4;
    const int ocol = lane & 15;

    if (gridDim.z > 1) {   // split-K: raw f32 partials
        float* Of = (float*)Out + (size_t)blockIdx.z * M * N;
        #pragma unroll
        for (int mr = 0; mr < 4; ++mr)
            #pragma unroll
            for (int nc = 0; nc < 4; ++nc)
                #pragma unroll
                for (int j = 0; j < 4; ++j) {
                    int gm = m0 + wr + mr * 16 + orow + j;
                    int gn = n0 + wc + nc * 16 + ocol;
                    Of[(size_t)gm * N + gn] = acc[mr][nc][j];
                }
        return;
    }

    float mcol[4], bcol[4];
    #pragma unroll
    for (int nc = 0; nc < 4; ++nc) {
        int gn = n0 + wc + nc * 16 + ocol;
        mcol[nc] = (maskMode == 0) ? 1.0f
                 : (maskMode == 1) ? mask[gn]
                                   : (mask[gn] > 0.8f ? 1.0f : 0.0f);
        bcol[nc] = (biasMode == 2) ? bias[gn] : 0.0f;
    }
    #pragma unroll
    for (int mr = 0; mr < 4; ++mr) {
        #pragma unroll
        for (int j = 0; j < 4; ++j) {
            int gm = m0 + wr + mr * 16 + orow + j;
            float brow = (biasMode == 1) ? bias[gm] : 0.0f;
            #pragma unroll
            for (int nc = 0; nc < 4; ++nc) {
                int gn = n0 + wc + nc * 16 + ocol;
                float v = acc[mr][nc][j] * mcol[nc] + brow + bcol[nc];
                if (doRelu) v = fmaxf(v, 0.0f);
                if (outBf16) ((ushort*)Out)[(size_t)gm * N + gn] = f2bf(v);
                else         ((float*)Out)[(size_t)gm * N + gn] = v;
            }
        }
    }
}

// sum 4 split-K partials -> bf16
__global__ __launch_bounds__(256) void reduce4(
    const float* __restrict__ P4, ushort* __restrict__ O, int len)
{
    int i = (blockIdx.x * 256 + threadIdx.x) * 4;
    float4 a = *(const float4*)&P4[i];
    float4 b = *(const float4*)&P4[(size_t)len + i];
    float4 c = *(const float4*)&P4[(size_t)2 * len + i];
    float4 d = *(const float4*)&P4[(size_t)3 * len + i];
    ushort4 o;
    o.x = f2bf(a.x + b.x + c.x + d.x);
    o.y = f2bf(a.y + b.y + c.y + d.y);
    o.z = f2bf(a.z + b.z + c.z + d.z);
    o.w = f2bf(a.w + b.w + c.w + d.w);
    *(ushort4*)&O[i] = o;
}

// ---------------------------------------------------------------------------
// Q and K projections, f32 (threshold-sensitive path). blockIdx.y: 0=Q, 1=K.
// Out[o][n] = scale * (mask[n] * sum_c W[o][c] X[c][n] + b[o]), M=64, K=512
// ---------------------------------------------------------------------------
__global__ __launch_bounds__(256) void qk_proj(
    const float* __restrict__ Wq_, const float* __restrict__ bq_,
    const float* __restrict__ qin, const float* __restrict__ qmask, int qmode,
    const float* __restrict__ Wk_, const float* __restrict__ bk_,
    const float* __restrict__ kin, const float* __restrict__ kmask, int kmode,
    float* __restrict__ Qout, float* __restrict__ Kout)
{
    const int sel = blockIdx.y;
    const float* W    = sel ? Wk_ : Wq_;
    const float* bias = sel ? bk_ : bq_;
    const float* X    = sel ? kin : qin;
    const float* mask = sel ? kmask : qmask;
    const int maskMode = sel ? kmode : qmode;
    const float scaleF = sel ? 1.0f : 0.125f;
    float* Out = sel ? Kout : Qout;

    __shared__ float As[16][65];
    __shared__ float Bs[16][65];
    const int tid = threadIdx.x;
    const int n0 = blockIdx.x * 64;
    const int ty = tid >> 4, tx = tid & 15;
    float acc[4][4] = {};

    for (int k0 = 0; k0 < 512; k0 += 16) {
        {
            int mm = tid >> 2, kq = (tid & 3) * 4;
            const float4 w4 = *(const float4*)&W[(size_t)mm * 512 + k0 + kq];
            As[kq + 0][mm] = w4.x; As[kq + 1][mm] = w4.y;
            As[kq + 2][mm] = w4.z; As[kq + 3][mm] = w4.w;
        }
        {
            int kk = tid >> 4, nq = (tid & 15) * 4;
            *(float4*)&Bs[kk][nq] = *(const float4*)&X[(size_t)(k0 + kk) * N_DIM + n0 + nq];
        }
        __syncthreads();
        #pragma unroll
        for (int kk = 0; kk < 16; ++kk) {
            float a[4], b[4];
            #pragma unroll
            for (int r = 0; r < 4; ++r) a[r] = As[kk][ty * 4 + r];
            #pragma unroll
            for (int c = 0; c < 4; ++c) b[c] = Bs[kk][tx * 4 + c];
            #pragma unroll
            for (int r = 0; r < 4; ++r)
                #pragma unroll
                for (int c = 0; c < 4; ++c)
                    acc[r][c] = fmaf(a[r], b[c], acc[r][c]);
        }
        __syncthreads();
    }

    float mk[4];
    #pragma unroll
    for (int c = 0; c < 4; ++c) {
        int n = n0 + tx * 4 + c;
        mk[c] = (maskMode == 0) ? 1.0f
              : (maskMode == 1) ? mask[n]
                                : (mask[n] > 0.8f ? 1.0f : 0.0f);
    }
    #pragma unroll
    for (int r = 0; r < 4; ++r) {
        float bo = bias[ty * 4 + r];
        float vals[4];
        #pragma unroll
        for (int c = 0; c < 4; ++c)
            vals[c] = (acc[r][c] * mk[c] + bo) * scaleF;
        float4 o = make_float4(vals[0], vals[1], vals[2], vals[3]);
        *(float4*)&Out[(size_t)(ty * 4 + r) * N_DIM + n0 + tx * 4] = o;
    }
}

// ---------------------------------------------------------------------------
// attn[i][j] = sum_t Q[t][i] * K[t][j]  (f32, threshold-exact) + global stats
// ---------------------------------------------------------------------------
__global__ __launch_bounds__(256) void attn_gemm(
    const float* __restrict__ Q, const float* __restrict__ Km,
    float* __restrict__ attn, float* __restrict__ part)
{
    __shared__ float Qs[64][65];
    __shared__ float Ks[64][65];
    const int tid = threadIdx.x;
    const int m0 = blockIdx.y * 64, n0 = blockIdx.x * 64;

    #pragma unroll
    for (int l = 0; l < 4; ++l) {
        int id = tid + l * 256;
        int kk = id >> 4, cq = (id & 15) * 4;
        *(float4*)&Qs[kk][cq] = *(const float4*)&Q[(size_t)kk * N_DIM + m0 + cq];
        *(float4*)&Ks[kk][cq] = *(const float4*)&Km[(size_t)kk * N_DIM + n0 + cq];
    }
    __syncthreads();

    const int ty = tid >> 4, tx = tid & 15;
    float acc[4][4] = {};
    #pragma unroll 16
    for (int kk = 0; kk < 64; ++kk) {
        float a[4], b[4];
        #pragma unroll
        for (int r = 0; r < 4; ++r) a[r] = Qs[kk][ty * 4 + r];
        #pragma unroll
        for (int c = 0; c < 4; ++c) b[c] = Ks[kk][tx * 4 + c];
        #pragma unroll
        for (int r = 0; r < 4; ++r)
            #pragma unroll
            for (int c = 0; c < 4; ++c)
                acc[r][c] = fmaf(a[r], b[c], acc[r][c]);
    }

    float lmax = -3.4e38f, lmin = 3.4e38f, lsum = 0.0f;
    #pragma unroll
    for (int r = 0; r < 4; ++r) {
        float4 o = make_float4(acc[r][0], acc[r][1], acc[r][2], acc[r][3]);
        *(float4*)&attn[(size_t)(m0 + ty * 4 + r) * N_DIM + n0 + tx * 4] = o;
        #pragma unroll
        for (int c = 0; c < 4; ++c) {
            float v = acc[r][c];
            lmax = fmaxf(lmax, v); lmin = fminf(lmin, v); lsum += v;
        }
    }

    __shared__ float red[256];
    int bid = blockIdx.y * gridDim.x + blockIdx.x;
    red[tid] = lmax; __syncthreads();
    for (int s = 128; s > 0; s >>= 1) { if (tid < s) red[tid] = fmaxf(red[tid], red[tid + s]); __syncthreads(); }
    if (tid == 0) part[bid] = red[0];
    __syncthreads();
    red[tid] = lmin; __syncthreads();
    for (int s = 128; s > 0; s >>= 1) { if (tid < s) red[tid] = fminf(red[tid], red[tid + s]); __syncthreads(); }
    if (tid == 0) part[4096 + bid] = red[0];
    __syncthreads();
    red[tid] = lsum; __syncthreads();
    for (int s = 128; s > 0; s >>= 1) { if (tid < s) red[tid] += red[tid + s]; __syncthreads(); }
    if (tid == 0) part[8192 + bid] = red[0];
}

__global__ __launch_bounds__(256) void attn_stats_fin(
    const float* __restrict__ part, float* __restrict__ stats, int useMax)
{
    __shared__ float rmax[256], rmin[256];
    __shared__ double rsum[256];
    int tid = threadIdx.x;
    float m1 = -3.4e38f, m2 = 3.4e38f; double s = 0.0;
    for (int i = tid; i < 4096; i += 256) {
        m1 = fmaxf(m1, part[i]);
        m2 = fminf(m2, part[4096 + i]);
        s += (double)part[8192 + i];
    }
    rmax[tid] = m1; rmin[tid] = m2; rsum[tid] = s;
    __syncthreads();
    for (int st = 128; st > 0; st >>= 1) {
        if (tid < st) {
            rmax[tid] = fmaxf(rmax[tid], rmax[tid + st]);
            rmin[tid] = fminf(rmin[tid], rmin[tid + st]);
            rsum[tid] += rsum[tid + st];
        }
        __syncthreads();
    }
    if (tid == 0) {
        float stat = useMax ? rmax[0] : rmin[0];
        float mean = (float)(rsum[0] / (double)NN_TOT);
        stats[0] = 0.5f * (stat + mean);
    }
}

// masked softmax per row; f32 in, bf16 out (P)
__global__ __launch_bounds__(256) void softmax_rows(
    const float* __restrict__ attn, const float* __restrict__ stats,
    ushort* __restrict__ P)
{
    const float thr = stats[0];
    const int tid = threadIdx.x;
    const float* row = attn + (size_t)blockIdx.x * N_DIM;
    float v[16];
    float lmax = -3.4e38f;
    #pragma unroll
    for (int k = 0; k < 16; ++k) {
        float a = row[tid + k * 256];
        a = (a < thr) ? -999.0f : a;
        v[k] = a;
        lmax = fmaxf(lmax, a);
    }
    __shared__ float red[256];
    red[tid] = lmax; __syncthreads();
    for (int s = 128; s > 0; s >>= 1) { if (tid < s) red[tid] = fmaxf(red[tid], red[tid + s]); __syncthreads(); }
    float m = red[0];
    __syncthreads();
    float lsum = 0.0f;
    #pragma unroll
    for (int k = 0; k < 16; ++k) { v[k] = __expf(v[k] - m); lsum += v[k]; }
    red[tid] = lsum; __syncthreads();
    for (int s = 128; s > 0; s >>= 1) { if (tid < s) red[tid] += red[tid + s]; __syncthreads(); }
    float inv = 1.0f / red[0];
    ushort* prow = P + (size_t)blockIdx.x * N_DIM;
    #pragma unroll
    for (int k = 0; k < 16; ++k) prow[tid + k * 256] = f2bf(v[k] * inv);
}

// ---------------------------------------------------------------------------
__global__ __launch_bounds__(256) void ln_partial(
    const float* __restrict__ X, float* __restrict__ part)
{
    __shared__ float rs[256], rq[256];
    int tid = threadIdx.x;
    size_t base = (size_t)blockIdx.x * 2048;
    float s = 0.0f, q = 0.0f;
    #pragma unroll
    for (int k = 0; k < 8; ++k) {
        float v = X[base + tid + k * 256];
        s += v; q = fmaf(v, v, q);
    }
    rs[tid] = s; rq[tid] = q; __syncthreads();
    for (int st = 128; st > 0; st >>= 1) {
        if (tid < st) { rs[tid] += rs[tid + st]; rq[tid] += rq[tid + st]; }
        __syncthreads();
    }
    if (tid == 0) { part[blockIdx.x] = rs[0]; part[1024 + blockIdx.x] = rq[0]; }
}

__global__ __launch_bounds__(256) void ln_fin(
    const float* __restrict__ part, float* __restrict__ stats)
{
    __shared__ double rs[256], rq[256];
    int tid = threadIdx.x;
    double s = 0.0, q = 0.0;
    for (int i = tid; i < 1024; i += 256) { s += part[i]; q += part[1024 + i]; }
    rs[tid] = s; rq[tid] = q; __syncthreads();
    for (int st = 128; st > 0; st >>= 1) {
        if (tid < st) { rs[tid] += rs[tid + st]; rq[tid] += rq[tid + st]; }
        __syncthreads();
    }
    if (tid == 0) {
        double mu = rs[0] / (double)CN;
        double var = rq[0] / (double)CN - mu * mu;
        stats[1] = (float)mu;
        stats[2] = (float)(1.0 / sqrt(var + 1e-5));
    }
}

__global__ __launch_bounds__(256) void gate_write(
    const float* __restrict__ H2, const float* __restrict__ stats,
    const float* __restrict__ gamma, const float* __restrict__ beta,
    const float* __restrict__ resid, const float* __restrict__ mask,
    float* __restrict__ out, int binarize)
{
    size_t idx = (size_t)blockIdx.x * 256 + threadIdx.x;
    int n = (int)(idx & (N_DIM - 1));
    float mu = stats[1], rs = stats[2];
    float normed = (H2[idx] - mu) * rs * gamma[idx] + beta[idx];
    float mv = mask[n];
    if (binarize) mv = (mv > 0.8f) ? 1.0f : 0.0f;
    out[idx] = normed * mv + resid[idx] * (1.0f - mv);
}

// ---------------------------------------------------------------------------
extern "C" void kernel_launch(void* const* d_in, const int* in_sizes, int n_in,
                              void* d_out, int out_size, void* d_ws, size_t ws_size,
                              hipStream_t stream)
{
    const float* x     = (const float*)d_in[0];
    const float* y     = (const float*)d_in[1];
    const float* s_m   = (const float*)d_in[2];
    const float* q_m   = (const float*)d_in[3];
    const float* Wq    = (const float*)d_in[4];
    const float* bq    = (const float*)d_in[5];
    const float* Wk    = (const float*)d_in[6];
    const float* bk    = (const float*)d_in[7];
    const float* Wv    = (const float*)d_in[8];
    const float* bv    = (const float*)d_in[9];
    const float* W1    = (const float*)d_in[10];
    const float* b1    = (const float*)d_in[11];
    const float* W2    = (const float*)d_in[12];
    const float* b2    = (const float*)d_in[13];
    const float* gamma = (const float*)d_in[14];
    const float* beta  = (const float*)d_in[15];
    float* out = (float*)d_out;

    float* ws = (float*)d_ws;
    // f32 region
    float*  ATT  = ws;                       // 16,777,216 f  (aliases: H2 @0, P4 @4M)
    float*  H2   = ATT;                      // 2,097,152 f
    float*  P4   = ATT + 4194304;            // 8,388,608 f (split-K partials)
    float*  Qb   = ws + 16777216;            // 262,144
    float*  Kb   = Qb + 262144;              // 262,144
    float*  PART = Kb + 262144;              // 12,288
    float*  STATS= PART + 12288;             // 64
    // bf16 region (ushort), offsets in floats
    ushort* xbT  = (ushort*)(STATS + 64);            // [4096][512]  (1,048,576 f)
    ushort* ybT  = xbT + 2097152;                    // [4096][512]
    ushort* Wvb  = ybT + 2097152;                    // [512][512]   (131,072 f)
    ushort* W1b  = Wvb + 262144;
    ushort* W2b  = W1b + 262144;
    ushort* Vb   = W2b + 262144;                     // [512][4096]
    ushort* Pb   = Vb + 2097152;                     // [4096][4096] (8,388,608 f)
    ushort* O1T  = Pb + 16777216;                    // [4096][512]
    ushort* H1T  = Pb;                               // alias: Pb dead when H1T written

    // one-time converts (cheap; rerun every call for determinism)
    tconv64<<<dim3(64, 8), 256, 0, stream>>>(x, xbT, 512, 4096);
    tconv64<<<dim3(64, 8), 256, 0, stream>>>(y, ybT, 512, 4096);
    cvtw<<<256, 256, 0, stream>>>(Wv, Wvb, 262144);
    cvtw<<<256, 256, 0, stream>>>(W1, W1b, 262144);
    cvtw<<<256, 256, 0, stream>>>(W2, W2b, 262144);

    for (int br = 0; br < 2; ++br) {
        const float*  qin    = (br == 0) ? x   : y;
        const float*  qmask  = (br == 0) ? s_m : q_m;
        int           qmode  = (br == 0) ? 1 : 2;
        const float*  kvin   = (br == 0) ? y   : x;
        const float*  kvmask = (br == 0) ? q_m : q_m;   // unused when mode 0
        int           kvmode = (br == 0) ? 2 : 0;
        const ushort* vbT    = (br == 0) ? ybT : xbT;

        // Q,K projections (f32, exact path)
        qk_proj<<<dim3(64, 2), 256, 0, stream>>>(
            Wq, bq, qin, qmask, qmode, Wk, bk, kvin, kvmask, kvmode, Qb, Kb);

        // V = Wv * (masked in) + bv  -> bf16 [512][4096]
        mfma_nt<<<dim3(32, 4, 1), 256, 0, stream>>>(
            Wvb, vbT, Vb, 512, 4096, 512, 512, bv, 1, kvmask, kvmode, 0, 1);

        // scores f32 + global stats
        attn_gemm<<<dim3(64, 64), 256, 0, stream>>>(Qb, Kb, ATT, PART);
        attn_stats_fin<<<1, 256, 0, stream>>>(PART, STATS, (br == 0) ? 1 : 0);
        softmax_rows<<<4096, 256, 0, stream>>>(ATT, STATS, Pb);

        // O1T[n][c] = sum_j P[n][j] V[c][j]   split-K x4 -> f32 partials
        mfma_nt<<<dim3(4, 32, 4), 256, 0, stream>>>(
            Pb, Vb, P4, 4096, 512, 4096, 1024, nullptr, 0, nullptr, 0, 0, 0);
        reduce4<<<2048, 256, 0, stream>>>(P4, O1T, 2097152);

        // H1T[n][o] = relu(sum_c O1T[n][c] W1[o][c] + b1[o]) -> bf16
        mfma_nt<<<dim3(4, 32, 1), 256, 0, stream>>>(
            O1T, W1b, H1T, 4096, 512, 512, 512, b1, 2, nullptr, 0, 1, 1);

        // H2[o][n] = sum_h W2[o][h] H1T[n][h] + b2[o] -> f32
        mfma_nt<<<dim3(32, 4, 1), 256, 0, stream>>>(
            W2b, H1T, H2, 512, 4096, 512, 512, b2, 1, nullptr, 0, 0, 0);

        ln_partial<<<1024, 256, 0, stream>>>(H2, PART);
        ln_fin<<<1, 256, 0, stream>>>(PART, STATS);
        gate_write<<<8192, 256, 0, stream>>>(H2, STATS, gamma, beta,
                                             (br == 0) ? x : y,
                                             (br == 0) ? s_m : q_m,
                                             out + (size_t)br * CN,
                                             (br == 0) ? 0 : 1);
    }
}

// Round 3
// 423.063 us; speedup vs baseline: 3.0545x; 1.0641x over previous
//
#include <hip/hip_runtime.h>
#include <math.h>

#define C_DIM 512
#define N_DIM 4096
#define CN (C_DIM * N_DIM)
#define NN_TOT ((long long)N_DIM * N_DIM)

typedef __attribute__((ext_vector_type(4))) float f32x4;
typedef __attribute__((ext_vector_type(8))) short short8;

__device__ __forceinline__ ushort f2bf(float f) {
    unsigned u = __float_as_uint(f);
    unsigned r = u + 0x7FFFu + ((u >> 16) & 1u);
    return (ushort)(r >> 16);
}
__device__ __forceinline__ float bf2f(ushort h) {
    return __uint_as_float((unsigned)h << 16);
}

__device__ __forceinline__ void gload16(const void* g, void* l) {
    __builtin_amdgcn_global_load_lds(
        (const __attribute__((address_space(1))) void*)g,
        (__attribute__((address_space(3))) void*)l, 16, 0, 0);
}

// ---------------------------------------------------------------------------
// Transpose + convert: X f32 [R][NC] -> XT bf16 [NC][R]
// ---------------------------------------------------------------------------
__global__ __launch_bounds__(256) void tconv64(
    const float* __restrict__ X, ushort* __restrict__ XT, int R, int NC)
{
    __shared__ float t[64][65];
    const int c0 = blockIdx.x * 64;
    const int r0 = blockIdx.y * 64;
    const int ty = threadIdx.x >> 4, tx = threadIdx.x & 15;
    #pragma unroll
    for (int i = 0; i < 4; ++i) {
        int r = ty + i * 16;
        float4 v = *(const float4*)&X[(size_t)(r0 + r) * NC + c0 + tx * 4];
        t[r][tx * 4 + 0] = v.x; t[r][tx * 4 + 1] = v.y;
        t[r][tx * 4 + 2] = v.z; t[r][tx * 4 + 3] = v.w;
    }
    __syncthreads();
    #pragma unroll
    for (int i = 0; i < 4; ++i) {
        int nn = ty + i * 16;
        ushort4 o;
        o.x = f2bf(t[tx * 4 + 0][nn]); o.y = f2bf(t[tx * 4 + 1][nn]);
        o.z = f2bf(t[tx * 4 + 2][nn]); o.w = f2bf(t[tx * 4 + 3][nn]);
        *(ushort4*)&XT[(size_t)(c0 + nn) * R + r0 + tx * 4] = o;
    }
}

__global__ __launch_bounds__(256) void cvtw(
    const float* __restrict__ in, ushort* __restrict__ out, int n)
{
    int i = (blockIdx.x * 256 + threadIdx.x) * 4;
    if (i < n) {
        float4 v = *(const float4*)&in[i];
        ushort4 o = { f2bf(v.x), f2bf(v.y), f2bf(v.z), f2bf(v.w) };
        *(ushort4*)&out[i] = o;
    }
}

// ---------------------------------------------------------------------------
// bf16 MFMA NT GEMM (unchanged from round 1, refcheck'd)
// ---------------------------------------------------------------------------
__global__ __launch_bounds__(256) void mfma_nt(
    const ushort* __restrict__ A, const ushort* __restrict__ B,
    void* __restrict__ Out, int M, int N, int K, int kLen,
    const float* __restrict__ bias, int biasMode,
    const float* __restrict__ mask, int maskMode,
    int doRelu, int outBf16)
{
    __shared__ ushort As[2][128 * 32];
    __shared__ ushort Bs[2][128 * 32];
    const int tid  = threadIdx.x;
    const int lane = tid & 63;
    const int wid  = tid >> 6;
    const int m0 = blockIdx.y * 128, n0 = blockIdx.x * 128;
    const int wr = (wid >> 1) * 64, wc = (wid & 1) * 64;
    const int kOff = blockIdx.z * kLen;

    const int srow  = wid * 32 + (lane >> 2);
    const int skoff = (lane & 3) * 8;
    const ushort* pA = A + (size_t)(m0 + srow) * K + kOff + skoff;
    const ushort* pB = B + (size_t)(n0 + srow) * K + kOff + skoff;

    auto stage = [&](int buf, int t) {
        const ushort* a = pA + (size_t)t * 32;
        const ushort* b = pB + (size_t)t * 32;
        gload16(a,                  &As[buf][(wid * 2 + 0) * 512]);
        gload16(a + (size_t)16 * K, &As[buf][(wid * 2 + 1) * 512]);
        gload16(b,                  &Bs[buf][(wid * 2 + 0) * 512]);
        gload16(b + (size_t)16 * K, &Bs[buf][(wid * 2 + 1) * 512]);
    };

    f32x4 acc[4][4] = {};
    const int fr = lane & 15;
    const int k8 = (lane >> 4) * 8;
    const int nt = kLen / 32;

    stage(0, 0);
    asm volatile("s_waitcnt vmcnt(0)" ::: "memory");
    __syncthreads();
    int cur = 0;
    for (int t = 0; t < nt; ++t) {
        if (t + 1 < nt) stage(cur ^ 1, t + 1);
        short8 af[4], bf[4];
        #pragma unroll
        for (int mr = 0; mr < 4; ++mr)
            af[mr] = *(const short8*)&As[cur][(wr + mr * 16 + fr) * 32 + k8];
        #pragma unroll
        for (int nc = 0; nc < 4; ++nc)
            bf[nc] = *(const short8*)&Bs[cur][(wc + nc * 16 + fr) * 32 + k8];
        #pragma unroll
        for (int mr = 0; mr < 4; ++mr)
            #pragma unroll
            for (int nc = 0; nc < 4; ++nc)
                acc[mr][nc] = __builtin_amdgcn_mfma_f32_16x16x32_bf16(
                    af[mr], bf[nc], acc[mr][nc], 0, 0, 0);
        asm volatile("s_waitcnt vmcnt(0)" ::: "memory");
        __syncthreads();
        cur ^= 1;
    }

    const int orow = (lane >> 4) * 4;
    const int ocol = lane & 15;

    if (gridDim.z > 1) {
        float* Of = (float*)Out + (size_t)blockIdx.z * M * N;
        #pragma unroll
        for (int mr = 0; mr < 4; ++mr)
            #pragma unroll
            for (int nc = 0; nc < 4; ++nc)
                #pragma unroll
                for (int j = 0; j < 4; ++j) {
                    int gm = m0 + wr + mr * 16 + orow + j;
                    int gn = n0 + wc + nc * 16 + ocol;
                    Of[(size_t)gm * N + gn] = acc[mr][nc][j];
                }
        return;
    }

    float mcol[4], bcol[4];
    #pragma unroll
    for (int nc = 0; nc < 4; ++nc) {
        int gn = n0 + wc + nc * 16 + ocol;
        mcol[nc] = (maskMode == 0) ? 1.0f
                 : (maskMode == 1) ? mask[gn]
                                   : (mask[gn] > 0.8f ? 1.0f : 0.0f);
        bcol[nc] = (biasMode == 2) ? bias[gn] : 0.0f;
    }
    #pragma unroll
    for (int mr = 0; mr < 4; ++mr) {
        #pragma unroll
        for (int j = 0; j < 4; ++j) {
            int gm = m0 + wr + mr * 16 + orow + j;
            float brow = (biasMode == 1) ? bias[gm] : 0.0f;
            #pragma unroll
            for (int nc = 0; nc < 4; ++nc) {
                int gn = n0 + wc + nc * 16 + ocol;
                float v = acc[mr][nc][j] * mcol[nc] + brow + bcol[nc];
                if (doRelu) v = fmaxf(v, 0.0f);
                if (outBf16) ((ushort*)Out)[(size_t)gm * N + gn] = f2bf(v);
                else         ((float*)Out)[(size_t)gm * N + gn] = v;
            }
        }
    }
}

// sum 4 split-K partials * per-row scale -> bf16
__global__ __launch_bounds__(256) void reduce4row(
    const float* __restrict__ P4, const float* __restrict__ invr,
    ushort* __restrict__ O, int len)
{
    int i = (blockIdx.x * 256 + threadIdx.x) * 4;
    int row = i >> 9;                    // [4096][512] layout
    float sc = invr[row];
    float4 a = *(const float4*)&P4[i];
    float4 b = *(const float4*)&P4[(size_t)len + i];
    float4 c = *(const float4*)&P4[(size_t)2 * len + i];
    float4 d = *(const float4*)&P4[(size_t)3 * len + i];
    ushort4 o;
    o.x = f2bf((a.x + b.x + c.x + d.x) * sc);
    o.y = f2bf((a.y + b.y + c.y + d.y) * sc);
    o.z = f2bf((a.z + b.z + c.z + d.z) * sc);
    o.w = f2bf((a.w + b.w + c.w + d.w) * sc);
    *(ushort4*)&O[i] = o;
}

// ---------------------------------------------------------------------------
// Q,K projections f32 (exact path). blockIdx.y: 0=Q, 1=K.
// ---------------------------------------------------------------------------
__global__ __launch_bounds__(256) void qk_proj(
    const float* __restrict__ Wq_, const float* __restrict__ bq_,
    const float* __restrict__ qin, const float* __restrict__ qmask, int qmode,
    const float* __restrict__ Wk_, const float* __restrict__ bk_,
    const float* __restrict__ kin, const float* __restrict__ kmask, int kmode,
    float* __restrict__ Qout, float* __restrict__ Kout)
{
    const int sel = blockIdx.y;
    const float* W    = sel ? Wk_ : Wq_;
    const float* bias = sel ? bk_ : bq_;
    const float* X    = sel ? kin : qin;
    const float* mask = sel ? kmask : qmask;
    const int maskMode = sel ? kmode : qmode;
    const float scaleF = sel ? 1.0f : 0.125f;
    float* Out = sel ? Kout : Qout;

    __shared__ float As[16][65];
    __shared__ float Bs[16][65];
    const int tid = threadIdx.x;
    const int n0 = blockIdx.x * 64;
    const int ty = tid >> 4, tx = tid & 15;
    float acc[4][4] = {};

    for (int k0 = 0; k0 < 512; k0 += 16) {
        {
            int mm = tid >> 2, kq = (tid & 3) * 4;
            const float4 w4 = *(const float4*)&W[(size_t)mm * 512 + k0 + kq];
            As[kq + 0][mm] = w4.x; As[kq + 1][mm] = w4.y;
            As[kq + 2][mm] = w4.z; As[kq + 3][mm] = w4.w;
        }
        {
            int kk = tid >> 4, nq = (tid & 15) * 4;
            *(float4*)&Bs[kk][nq] = *(const float4*)&X[(size_t)(k0 + kk) * N_DIM + n0 + nq];
        }
        __syncthreads();
        #pragma unroll
        for (int kk = 0; kk < 16; ++kk) {
            float a[4], b[4];
            #pragma unroll
            for (int r = 0; r < 4; ++r) a[r] = As[kk][ty * 4 + r];
            #pragma unroll
            for (int c = 0; c < 4; ++c) b[c] = Bs[kk][tx * 4 + c];
            #pragma unroll
            for (int r = 0; r < 4; ++r)
                #pragma unroll
                for (int c = 0; c < 4; ++c)
                    acc[r][c] = fmaf(a[r], b[c], acc[r][c]);
        }
        __syncthreads();
    }

    float mk[4];
    #pragma unroll
    for (int c = 0; c < 4; ++c) {
        int n = n0 + tx * 4 + c;
        mk[c] = (maskMode == 0) ? 1.0f
              : (maskMode == 1) ? mask[n]
                                : (mask[n] > 0.8f ? 1.0f : 0.0f);
    }
    #pragma unroll
    for (int r = 0; r < 4; ++r) {
        float bo = bias[ty * 4 + r];
        float vals[4];
        #pragma unroll
        for (int c = 0; c < 4; ++c)
            vals[c] = (acc[r][c] * mk[c] + bo) * scaleF;
        float4 o = make_float4(vals[0], vals[1], vals[2], vals[3]);
        *(float4*)&Out[(size_t)(ty * 4 + r) * N_DIM + n0 + tx * 4] = o;
    }
}

// ---------------------------------------------------------------------------
// Split Q,K (f32 [64][4096]) into bf16x3 concat fragment-order layout:
//   QF/KF: [blk=256][kstep=6][lane=64][8 ushorts]
//   lane = quad*16+fr -> row = blk*16+fr, d = (kstep&1)*32 + quad*8 + j
//   cat: Q = [hi|hi|lo] (kstep 0-1,2-3,4-5), K = [hi|lo|hi]
// ---------------------------------------------------------------------------
__global__ __launch_bounds__(256) void splitcat(
    const float* __restrict__ Qb, const float* __restrict__ Kb,
    ushort* __restrict__ QF, ushort* __restrict__ KF)
{
    int gid = blockIdx.x * 256 + threadIdx.x;     // 2*256*6*64 total
    int lane = gid & 63;
    int rest = gid >> 6;                          // 0..3071
    int kstep = rest % 6;
    int bt    = rest / 6;                         // 0..511
    int blk   = bt & 255;
    int tens  = bt >> 8;
    const float* src = tens ? Kb : Qb;
    ushort* dst = tens ? KF : QF;
    int fr = lane & 15, quad = lane >> 4;
    int n = blk * 16 + fr;
    bool useLo = tens ? (kstep >= 2 && kstep < 4) : (kstep >= 4);
    ushort o[8];
    #pragma unroll
    for (int j = 0; j < 8; ++j) {
        int d = (kstep & 1) * 32 + quad * 8 + j;
        float v = src[(size_t)d * N_DIM + n];
        ushort hi = f2bf(v);
        if (useLo) o[j] = f2bf(v - bf2f(hi));
        else       o[j] = hi;
    }
    size_t base = ((size_t)(blk * 6 + kstep) * 64 + lane) * 8;
    *(ushort4*)&dst[base]     = *(ushort4*)&o[0];
    *(ushort4*)&dst[base + 4] = *(ushort4*)&o[4];
}

// shared MFMA core for the two score passes (identical arithmetic order!)
__device__ __forceinline__ void scores_mfma(
    const ushort* __restrict__ QF, const ushort* __restrict__ KF,
    int m0, int n0, int wr, int wc, int lane, f32x4 acc[4][4])
{
    const int blkA0 = (m0 + wr) >> 4;
    const int blkB0 = (n0 + wc) >> 4;
    #pragma unroll
    for (int s = 0; s < 6; ++s) {
        short8 af[4], bf[4];
        #pragma unroll
        for (int mr = 0; mr < 4; ++mr)
            af[mr] = *(const short8*)&QF[((size_t)((blkA0 + mr) * 6 + s) * 64 + lane) * 8];
        #pragma unroll
        for (int nc = 0; nc < 4; ++nc)
            bf[nc] = *(const short8*)&KF[((size_t)((blkB0 + nc) * 6 + s) * 64 + lane) * 8];
        #pragma unroll
        for (int mr = 0; mr < 4; ++mr)
            #pragma unroll
            for (int nc = 0; nc < 4; ++nc)
                acc[mr][nc] = __builtin_amdgcn_mfma_f32_16x16x32_bf16(
                    af[mr], bf[nc], acc[mr][nc], 0, 0, 0);
    }
}

// pass 1: global max/min/sum partials + per-row max partials (no score store)
__global__ __launch_bounds__(256) void scores_pass1(
    const ushort* __restrict__ QF, const ushort* __restrict__ KF,
    float* __restrict__ part, float* __restrict__ rowmaxp)
{
    const int lane = threadIdx.x & 63, wid = threadIdx.x >> 6;
    const int m0 = blockIdx.y * 128, n0 = blockIdx.x * 128;
    const int wr = (wid >> 1) * 64, wc = (wid & 1) * 64;
    f32x4 acc[4][4] = {};
    scores_mfma(QF, KF, m0, n0, wr, wc, lane, acc);

    float lmax = -3.4e38f, lmin = 3.4e38f, lsum = 0.0f;
    float rmx[4][4];
    #pragma unroll
    for (int mr = 0; mr < 4; ++mr)
        #pragma unroll
        for (int j = 0; j < 4; ++j) rmx[mr][j] = -3.4e38f;
    #pragma unroll
    for (int mr = 0; mr < 4; ++mr)
        #pragma unroll
        for (int nc = 0; nc < 4; ++nc)
            #pragma unroll
            for (int j = 0; j < 4; ++j) {
                float v = acc[mr][nc][j];
                lsum += v; lmax = fmaxf(lmax, v); lmin = fminf(lmin, v);
                rmx[mr][j] = fmaxf(rmx[mr][j], v);
            }
    #pragma unroll
    for (int m = 1; m < 16; m <<= 1)
        #pragma unroll
        for (int mr = 0; mr < 4; ++mr)
            #pragma unroll
            for (int j = 0; j < 4; ++j)
                rmx[mr][j] = fmaxf(rmx[mr][j], __shfl_xor(rmx[mr][j], m, 64));

    __shared__ float wrm[2][128];
    const int orow = (lane >> 4) * 4;
    if ((lane & 15) == 0) {
        #pragma unroll
        for (int mr = 0; mr < 4; ++mr)
            #pragma unroll
            for (int j = 0; j < 4; ++j)
                wrm[wid & 1][wr + mr * 16 + orow + j] = rmx[mr][j];
    }
    __syncthreads();
    if (threadIdx.x < 128) {
        float v = fmaxf(wrm[0][threadIdx.x], wrm[1][threadIdx.x]);
        rowmaxp[(size_t)blockIdx.x * 4096 + m0 + threadIdx.x] = v;
    }

    __shared__ float red[256];
    const int tid = threadIdx.x;
    const int bid = blockIdx.y * 32 + blockIdx.x;
    __syncthreads();
    red[tid] = lmax; __syncthreads();
    for (int s = 128; s > 0; s >>= 1) { if (tid < s) red[tid] = fmaxf(red[tid], red[tid + s]); __syncthreads(); }
    if (tid == 0) part[bid] = red[0];
    __syncthreads();
    red[tid] = lmin; __syncthreads();
    for (int s = 128; s > 0; s >>= 1) { if (tid < s) red[tid] = fminf(red[tid], red[tid + s]); __syncthreads(); }
    if (tid == 0) part[1024 + bid] = red[0];
    __syncthreads();
    red[tid] = lsum; __syncthreads();
    for (int s = 128; s > 0; s >>= 1) { if (tid < s) red[tid] += red[tid + s]; __syncthreads(); }
    if (tid == 0) part[2048 + bid] = red[0];
}

__global__ __launch_bounds__(256) void stats_fin2(
    const float* __restrict__ part, float* __restrict__ stats, int useMax)
{
    __shared__ float rmax[256], rmin[256];
    __shared__ double rsum[256];
    int tid = threadIdx.x;
    float m1 = -3.4e38f, m2 = 3.4e38f; double s = 0.0;
    for (int i = tid; i < 1024; i += 256) {
        m1 = fmaxf(m1, part[i]);
        m2 = fminf(m2, part[1024 + i]);
        s += (double)part[2048 + i];
    }
    rmax[tid] = m1; rmin[tid] = m2; rsum[tid] = s;
    __syncthreads();
    for (int st = 128; st > 0; st >>= 1) {
        if (tid < st) {
            rmax[tid] = fmaxf(rmax[tid], rmax[tid + st]);
            rmin[tid] = fminf(rmin[tid], rmin[tid + st]);
            rsum[tid] += rsum[tid + st];
        }
        __syncthreads();
    }
    if (tid == 0) {
        float stat = useMax ? rmax[0] : rmin[0];
        float mean = (float)(rsum[0] / (double)NN_TOT);
        stats[0] = 0.5f * (stat + mean);
    }
}

// rowm[r] = rowmax if rowmax >= thr else -1e30 (all-masked flag)
__global__ __launch_bounds__(256) void row_fin(
    const float* __restrict__ rowmaxp, const float* __restrict__ stats,
    float* __restrict__ rowm)
{
    int r = blockIdx.x * 256 + threadIdx.x;
    float thr = stats[0];
    float m = -3.4e38f;
    #pragma unroll 8
    for (int b = 0; b < 32; ++b) m = fmaxf(m, rowmaxp[(size_t)b * 4096 + r]);
    rowm[r] = (m >= thr) ? m : -1e30f;
}

// pass 2: recompute scores, write e = exp(s - m) bf16 (unnormalized) + rowsum partials
__global__ __launch_bounds__(256) void scores_pass2(
    const ushort* __restrict__ QF, const ushort* __restrict__ KF,
    const float* __restrict__ stats, const float* __restrict__ rowm,
    ushort* __restrict__ P, float* __restrict__ rowsump)
{
    const int lane = threadIdx.x & 63, wid = threadIdx.x >> 6;
    const int m0 = blockIdx.y * 128, n0 = blockIdx.x * 128;
    const int wr = (wid >> 1) * 64, wc = (wid & 1) * 64;
    f32x4 acc[4][4] = {};
    scores_mfma(QF, KF, m0, n0, wr, wc, lane, acc);

    const float thr = stats[0];
    const int orow = (lane >> 4) * 4;
    const int ocol = lane & 15;
    float rm[4][4], rs[4][4];
    #pragma unroll
    for (int mr = 0; mr < 4; ++mr)
        #pragma unroll
        for (int j = 0; j < 4; ++j) {
            rm[mr][j] = rowm[m0 + wr + mr * 16 + orow + j];
            rs[mr][j] = 0.0f;
        }
    #pragma unroll
    for (int mr = 0; mr < 4; ++mr)
        #pragma unroll
        for (int nc = 0; nc < 4; ++nc)
            #pragma unroll
            for (int j = 0; j < 4; ++j) {
                float s = acc[mr][nc][j];
                float m = rm[mr][j];
                float e = (s < thr) ? 0.0f : __expf(s - m);
                if (m < -1e29f) e = 1.0f;          // fully-masked row -> uniform
                ushort h = f2bf(e);
                rs[mr][j] += bf2f(h);
                P[(size_t)(m0 + wr + mr * 16 + orow + j) * N_DIM
                  + n0 + wc + nc * 16 + ocol] = h;
            }
    #pragma unroll
    for (int m = 1; m < 16; m <<= 1)
        #pragma unroll
        for (int mr = 0; mr < 4; ++mr)
            #pragma unroll
            for (int j = 0; j < 4; ++j)
                rs[mr][j] += __shfl_xor(rs[mr][j], m, 64);

    __shared__ float wrs[2][128];
    if ((lane & 15) == 0) {
        #pragma unroll
        for (int mr = 0; mr < 4; ++mr)
            #pragma unroll
            for (int j = 0; j < 4; ++j)
                wrs[wid & 1][wr + mr * 16 + orow + j] = rs[mr][j];
    }
    __syncthreads();
    if (threadIdx.x < 128)
        rowsump[(size_t)blockIdx.x * 4096 + m0 + threadIdx.x] =
            wrs[0][threadIdx.x] + wrs[1][threadIdx.x];
}

__global__ __launch_bounds__(256) void rsum_fin(
    const float* __restrict__ rowsump, float* __restrict__ invr)
{
    int r = blockIdx.x * 256 + threadIdx.x;
    float s = 0.0f;
    #pragma unroll 8
    for (int b = 0; b < 32; ++b) s += rowsump[(size_t)b * 4096 + r];
    invr[r] = 1.0f / s;
}

// ---------------------------------------------------------------------------
__global__ __launch_bounds__(256) void ln_partial(
    const float* __restrict__ X, float* __restrict__ part)
{
    __shared__ float rs[256], rq[256];
    int tid = threadIdx.x;
    size_t base = (size_t)blockIdx.x * 2048;
    float s = 0.0f, q = 0.0f;
    #pragma unroll
    for (int k = 0; k < 8; ++k) {
        float v = X[base + tid + k * 256];
        s += v; q = fmaf(v, v, q);
    }
    rs[tid] = s; rq[tid] = q; __syncthreads();
    for (int st = 128; st > 0; st >>= 1) {
        if (tid < st) { rs[tid] += rs[tid + st]; rq[tid] += rq[tid + st]; }
        __syncthreads();
    }
    if (tid == 0) { part[blockIdx.x] = rs[0]; part[1024 + blockIdx.x] = rq[0]; }
}

__global__ __launch_bounds__(256) void ln_fin(
    const float* __restrict__ part, float* __restrict__ stats)
{
    __shared__ double rs[256], rq[256];
    int tid = threadIdx.x;
    double s = 0.0, q = 0.0;
    for (int i = tid; i < 1024; i += 256) { s += part[i]; q += part[1024 + i]; }
    rs[tid] = s; rq[tid] = q; __syncthreads();
    for (int st = 128; st > 0; st >>= 1) {
        if (tid < st) { rs[tid] += rs[tid + st]; rq[tid] += rq[tid + st]; }
        __syncthreads();
    }
    if (tid == 0) {
        double mu = rs[0] / (double)CN;
        double var = rq[0] / (double)CN - mu * mu;
        stats[1] = (float)mu;
        stats[2] = (float)(1.0 / sqrt(var + 1e-5));
    }
}

__global__ __launch_bounds__(256) void gate_write(
    const float* __restrict__ H2, const float* __restrict__ stats,
    const float* __restrict__ gamma, const float* __restrict__ beta,
    const float* __restrict__ resid, const float* __restrict__ mask,
    float* __restrict__ out, int binarize)
{
    size_t idx = (size_t)blockIdx.x * 256 + threadIdx.x;
    int n = (int)(idx & (N_DIM - 1));
    float mu = stats[1], rs = stats[2];
    float normed = (H2[idx] - mu) * rs * gamma[idx] + beta[idx];
    float mv = mask[n];
    if (binarize) mv = (mv > 0.8f) ? 1.0f : 0.0f;
    out[idx] = normed * mv + resid[idx] * (1.0f - mv);
}

// ---------------------------------------------------------------------------
extern "C" void kernel_launch(void* const* d_in, const int* in_sizes, int n_in,
                              void* d_out, int out_size, void* d_ws, size_t ws_size,
                              hipStream_t stream)
{
    const float* x     = (const float*)d_in[0];
    const float* y     = (const float*)d_in[1];
    const float* s_m   = (const float*)d_in[2];
    const float* q_m   = (const float*)d_in[3];
    const float* Wq    = (const float*)d_in[4];
    const float* bq    = (const float*)d_in[5];
    const float* Wk    = (const float*)d_in[6];
    const float* bk    = (const float*)d_in[7];
    const float* Wv    = (const float*)d_in[8];
    const float* bv    = (const float*)d_in[9];
    const float* W1    = (const float*)d_in[10];
    const float* b1    = (const float*)d_in[11];
    const float* W2    = (const float*)d_in[12];
    const float* b2    = (const float*)d_in[13];
    const float* gamma = (const float*)d_in[14];
    const float* beta  = (const float*)d_in[15];
    float* out = (float*)d_out;

    float* ws    = (float*)d_ws;
    float* Qb    = ws;                      // 262144
    float* Kb    = Qb + 262144;             // 262144
    float* H2    = Kb + 262144;             // 2097152
    float* P4    = H2 + 2097152;            // 8388608
    float* PART  = P4 + 8388608;            // 4096
    float* RMAXP = PART + 4096;             // 131072
    float* RSUMP = RMAXP + 131072;          // 131072
    float* ROWM  = RSUMP + 131072;          // 4096
    float* INVR  = ROWM + 4096;             // 4096
    float* STATS = INVR + 4096;             // 64
    ushort* xbT  = (ushort*)(STATS + 64);   // [4096][512]
    ushort* ybT  = xbT + 2097152;
    ushort* Wvb  = ybT + 2097152;           // 262144 each
    ushort* W1b  = Wvb + 262144;
    ushort* W2b  = W1b + 262144;
    ushort* Vb   = W2b + 262144;            // [512][4096]
    ushort* QF   = Vb + 2097152;            // 786432 (4096 x 192)
    ushort* KF   = QF + 786432;
    ushort* Pe   = KF + 786432;             // [4096][4096]
    ushort* O1T  = Pe + 16777216;           // [4096][512]
    ushort* H1T  = O1T + 2097152;

    tconv64<<<dim3(64, 8), 256, 0, stream>>>(x, xbT, 512, 4096);
    tconv64<<<dim3(64, 8), 256, 0, stream>>>(y, ybT, 512, 4096);
    cvtw<<<256, 256, 0, stream>>>(Wv, Wvb, 262144);
    cvtw<<<256, 256, 0, stream>>>(W1, W1b, 262144);
    cvtw<<<256, 256, 0, stream>>>(W2, W2b, 262144);

    for (int br = 0; br < 2; ++br) {
        const float*  qin    = (br == 0) ? x   : y;
        const float*  qmask  = (br == 0) ? s_m : q_m;
        int           qmode  = (br == 0) ? 1 : 2;
        const float*  kvin   = (br == 0) ? y   : x;
        const float*  kvmask = (br == 0) ? q_m : q_m;
        int           kvmode = (br == 0) ? 2 : 0;
        const ushort* vbT    = (br == 0) ? ybT : xbT;

        qk_proj<<<dim3(64, 2), 256, 0, stream>>>(
            Wq, bq, qin, qmask, qmode, Wk, bk, kvin, kvmask, kvmode, Qb, Kb);
        splitcat<<<768, 256, 0, stream>>>(Qb, Kb, QF, KF);

        mfma_nt<<<dim3(32, 4, 1), 256, 0, stream>>>(
            Wvb, vbT, Vb, 512, 4096, 512, 512, bv, 1, kvmask, kvmode, 0, 1);

        scores_pass1<<<dim3(32, 32), 256, 0, stream>>>(QF, KF, PART, RMAXP);
        stats_fin2<<<1, 256, 0, stream>>>(PART, STATS, (br == 0) ? 1 : 0);
        row_fin<<<16, 256, 0, stream>>>(RMAXP, STATS, ROWM);
        scores_pass2<<<dim3(32, 32), 256, 0, stream>>>(QF, KF, STATS, ROWM, Pe, RSUMP);
        rsum_fin<<<16, 256, 0, stream>>>(RSUMP, INVR);

        mfma_nt<<<dim3(4, 32, 4), 256, 0, stream>>>(
            Pe, Vb, P4, 4096, 512, 4096, 1024, nullptr, 0, nullptr, 0, 0, 0);
        reduce4row<<<2048, 256, 0, stream>>>(P4, INVR, O1T, 2097152);

        mfma_nt<<<dim3(4, 32, 1), 256, 0, stream>>>(
            O1T, W1b, H1T, 4096, 512, 512, 512, b1, 2, nullptr, 0, 1, 1);
        mfma_nt<<<dim3(32, 4, 1), 256, 0, stream>>>(
            W2b, H1T, H2, 512, 4096, 512, 512, b2, 1, nullptr, 0, 0, 0);

        ln_partial<<<1024, 256, 0, stream>>>(H2, PART);
        ln_fin<<<1, 256, 0, stream>>>(PART, STATS);
        gate_write<<<8192, 256, 0, stream>>>(H2, STATS, gamma, beta,
                                             (br == 0) ? x : y,
                                             (br == 0) ? s_m : q_m,
                                             out + (size_t)br * CN,
                                             (br == 0) ? 0 : 1);
    }
}

// Round 4
// 247.052 us; speedup vs baseline: 5.2306x; 1.7124x over previous
//
#include <hip/hip_runtime.h>
#include <math.h>

#define C_DIM 512
#define N_DIM 4096
#define CN (C_DIM * N_DIM)
#define SZO (N_DIM * C_DIM)          // 2,097,152 (pixel x channel)
#define NN ((size_t)N_DIM * N_DIM)
#define NN_TOT ((long long)N_DIM * N_DIM)

typedef __attribute__((ext_vector_type(4))) float f32x4;
typedef __attribute__((ext_vector_type(8))) short short8;

__device__ __forceinline__ ushort f2bf(float f) {
    unsigned u = __float_as_uint(f);
    unsigned r = u + 0x7FFFu + ((u >> 16) & 1u);
    return (ushort)(r >> 16);
}
__device__ __forceinline__ float bf2f(ushort h) {
    return __uint_as_float((unsigned)h << 16);
}

__device__ __forceinline__ void gload16(const void* g, void* l) {
    __builtin_amdgcn_global_load_lds(
        (const __attribute__((address_space(1))) void*)g,
        (__attribute__((address_space(3))) void*)l, 16, 0, 0);
}

// ---------------------------------------------------------------------------
// Transpose + convert: X f32 [512][4096] -> XT bf16 [4096][512], batched x/y
// ---------------------------------------------------------------------------
__global__ __launch_bounds__(256) void tconv64(
    const float* __restrict__ x, const float* __restrict__ y,
    ushort* __restrict__ xbT, ushort* __restrict__ ybT)
{
    const float* X = blockIdx.z ? y : x;
    ushort* XT = blockIdx.z ? ybT : xbT;
    __shared__ float t[64][65];
    const int c0 = blockIdx.x * 64;   // pixel dim
    const int r0 = blockIdx.y * 64;   // channel dim
    const int ty = threadIdx.x >> 4, tx = threadIdx.x & 15;
    #pragma unroll
    for (int i = 0; i < 4; ++i) {
        int r = ty + i * 16;
        float4 v = *(const float4*)&X[(size_t)(r0 + r) * N_DIM + c0 + tx * 4];
        t[r][tx * 4 + 0] = v.x; t[r][tx * 4 + 1] = v.y;
        t[r][tx * 4 + 2] = v.z; t[r][tx * 4 + 3] = v.w;
    }
    __syncthreads();
    #pragma unroll
    for (int i = 0; i < 4; ++i) {
        int nn = ty + i * 16;
        ushort4 o;
        o.x = f2bf(t[tx * 4 + 0][nn]); o.y = f2bf(t[tx * 4 + 1][nn]);
        o.z = f2bf(t[tx * 4 + 2][nn]); o.w = f2bf(t[tx * 4 + 3][nn]);
        *(ushort4*)&XT[(size_t)(c0 + nn) * C_DIM + r0 + tx * 4] = o;
    }
}

// batched weight converts (Wv, W1, W2 all 512x512)
__global__ __launch_bounds__(256) void cvtw3(
    const float* __restrict__ Wv, const float* __restrict__ W1,
    const float* __restrict__ W2, ushort* __restrict__ Wvb,
    ushort* __restrict__ W1b, ushort* __restrict__ W2b)
{
    const float* in  = (blockIdx.y == 0) ? Wv : (blockIdx.y == 1) ? W1 : W2;
    ushort*      out = (blockIdx.y == 0) ? Wvb : (blockIdx.y == 1) ? W1b : W2b;
    int i = (blockIdx.x * 256 + threadIdx.x) * 4;
    float4 v = *(const float4*)&in[i];
    ushort4 o = { f2bf(v.x), f2bf(v.y), f2bf(v.z), f2bf(v.w) };
    *(ushort4*)&out[i] = o;
}

// ---------------------------------------------------------------------------
// Generic bf16 MFMA NT GEMM, tile BM x BN, BK=32, 4 waves, double-buffered
// LDS via global_load_lds. Branch-batched: z = br*nkz + kz.
// nkz>1: f32 split-K partials at Out + z*M*N. nkz==1: full epilogue.
// ---------------------------------------------------------------------------
template<int BM, int BN>
__global__ __launch_bounds__(256) void mfma_g(
    const ushort* __restrict__ A0, const ushort* __restrict__ A1,
    const ushort* __restrict__ B0, const ushort* __restrict__ B1,
    void* __restrict__ Out, size_t outBrStride,
    int M, int N, int K, int kLen, int nkz,
    const float* __restrict__ bias, int biasMode,   // 0 none, 1 per-row m, 2 per-col n
    const float* __restrict__ mask0, int mm0,
    const float* __restrict__ mask1, int mm1,       // per-col n mask
    int doRelu, int outBf16)
{
    constexpr int WAVES_M = BM / 64;
    constexpr int WAVES_N = 4 / WAVES_M;
    constexpr int WN = BN / WAVES_N;
    constexpr int FM = 4;            // 64/16
    constexpr int FN = WN / 16;
    constexpr int NCHUNK = (BM + BN) / 16;

    __shared__ ushort As[2][BM * 32];
    __shared__ ushort Bs[2][BN * 32];
    const int tid  = threadIdx.x;
    const int lane = tid & 63;
    const int wid  = tid >> 6;
    const int z  = blockIdx.z;
    const int br = z / nkz;
    const int kz = z % nkz;
    const ushort* A = br ? A1 : A0;
    const ushort* B = br ? B1 : B0;
    const float* mask = br ? mask1 : mask0;
    const int maskMode = br ? mm1 : mm0;

    const int m0 = blockIdx.y * BM, n0 = blockIdx.x * BN;
    const int wm = wid / WAVES_N, wn = wid % WAVES_N;
    const int wr = wm * 64, wc = wn * WN;
    const int kOff = kz * kLen;
    const int lrow = lane >> 2;
    const int lk   = (lane & 3) * 8;

    auto stage = [&](int buf, int t) {
        #pragma unroll
        for (int c = wid; c < NCHUNK; c += 4) {
            if (c < BM / 16) {
                gload16(A + (size_t)(m0 + c * 16 + lrow) * K + kOff + t * 32 + lk,
                        &As[buf][c * 512]);
            } else {
                int cb = c - BM / 16;
                gload16(B + (size_t)(n0 + cb * 16 + lrow) * K + kOff + t * 32 + lk,
                        &Bs[buf][cb * 512]);
            }
        }
    };

    f32x4 acc[FM][FN] = {};
    const int fr = lane & 15;
    const int k8 = (lane >> 4) * 8;
    const int nt = kLen / 32;

    stage(0, 0);
    asm volatile("s_waitcnt vmcnt(0)" ::: "memory");
    __syncthreads();
    int cur = 0;
    for (int t = 0; t < nt; ++t) {
        if (t + 1 < nt) stage(cur ^ 1, t + 1);
        short8 af[FM], bf[FN];
        #pragma unroll
        for (int mr = 0; mr < FM; ++mr)
            af[mr] = *(const short8*)&As[cur][(wr + mr * 16 + fr) * 32 + k8];
        #pragma unroll
        for (int nc = 0; nc < FN; ++nc)
            bf[nc] = *(const short8*)&Bs[cur][(wc + nc * 16 + fr) * 32 + k8];
        #pragma unroll
        for (int mr = 0; mr < FM; ++mr)
            #pragma unroll
            for (int nc = 0; nc < FN; ++nc)
                acc[mr][nc] = __builtin_amdgcn_mfma_f32_16x16x32_bf16(
                    af[mr], bf[nc], acc[mr][nc], 0, 0, 0);
        asm volatile("s_waitcnt vmcnt(0)" ::: "memory");
        __syncthreads();
        cur ^= 1;
    }

    const int orow = (lane >> 4) * 4;
    const int ocol = lane & 15;

    if (nkz > 1) {   // split-K: raw f32 partials
        float* Of = (float*)Out + (size_t)z * M * N;
        #pragma unroll
        for (int mr = 0; mr < FM; ++mr)
            #pragma unroll
            for (int nc = 0; nc < FN; ++nc)
                #pragma unroll
                for (int j = 0; j < 4; ++j) {
                    int gm = m0 + wr + mr * 16 + orow + j;
                    int gn = n0 + wc + nc * 16 + ocol;
                    Of[(size_t)gm * N + gn] = acc[mr][nc][j];
                }
        return;
    }

    float mcol[FN], bcol[FN];
    #pragma unroll
    for (int nc = 0; nc < FN; ++nc) {
        int gn = n0 + wc + nc * 16 + ocol;
        mcol[nc] = (maskMode == 0) ? 1.0f
                 : (maskMode == 1) ? mask[gn]
                                   : (mask[gn] > 0.8f ? 1.0f : 0.0f);
        bcol[nc] = (biasMode == 2) ? bias[gn] : 0.0f;
    }
    ushort* Obf = (ushort*)Out + (size_t)br * outBrStride;
    float*  Of  = (float*)Out + (size_t)br * outBrStride;
    #pragma unroll
    for (int mr = 0; mr < FM; ++mr) {
        #pragma unroll
        for (int j = 0; j < 4; ++j) {
            int gm = m0 + wr + mr * 16 + orow + j;
            float brow = (biasMode == 1) ? bias[gm] : 0.0f;
            #pragma unroll
            for (int nc = 0; nc < FN; ++nc) {
                int gn = n0 + wc + nc * 16 + ocol;
                float v = acc[mr][nc][j] * mcol[nc] + brow + bcol[nc];
                if (doRelu) v = fmaxf(v, 0.0f);
                if (outBf16) Obf[(size_t)gm * N + gn] = f2bf(v);
                else         Of[(size_t)gm * N + gn] = v;
            }
        }
    }
}

// ---------------------------------------------------------------------------
// Raw Q/K projections, f32 split-K: PX[kz][src][128][4096], rows 0-63 = Wq.X,
// 64-127 = Wk.X.  grid (64 ntile, 4 = src*2+mt, 4 kz)
// ---------------------------------------------------------------------------
__global__ __launch_bounds__(256) void qkraw(
    const float* __restrict__ Wq, const float* __restrict__ Wk,
    const float* __restrict__ x, const float* __restrict__ y,
    float* __restrict__ PX)
{
    const int mt   = blockIdx.y & 1;
    const int srcT = blockIdx.y >> 1;
    const int kz   = blockIdx.z;
    const float* W = mt ? Wk : Wq;
    const float* X = srcT ? y : x;

    __shared__ float As[16][65];
    __shared__ float Bs[16][65];
    const int tid = threadIdx.x;
    const int n0 = blockIdx.x * 64;
    const int ty = tid >> 4, tx = tid & 15;
    float acc[4][4] = {};
    const int kbase = kz * 128;

    for (int k0 = kbase; k0 < kbase + 128; k0 += 16) {
        {
            int mm = tid >> 2, kq = (tid & 3) * 4;
            const float4 w4 = *(const float4*)&W[(size_t)mm * 512 + k0 + kq];
            As[kq + 0][mm] = w4.x; As[kq + 1][mm] = w4.y;
            As[kq + 2][mm] = w4.z; As[kq + 3][mm] = w4.w;
        }
        {
            int kk = tid >> 4, nq = (tid & 15) * 4;
            *(float4*)&Bs[kk][nq] = *(const float4*)&X[(size_t)(k0 + kk) * N_DIM + n0 + nq];
        }
        __syncthreads();
        #pragma unroll
        for (int kk = 0; kk < 16; ++kk) {
            float a[4], b[4];
            #pragma unroll
            for (int r = 0; r < 4; ++r) a[r] = As[kk][ty * 4 + r];
            #pragma unroll
            for (int c = 0; c < 4; ++c) b[c] = Bs[kk][tx * 4 + c];
            #pragma unroll
            for (int r = 0; r < 4; ++r)
                #pragma unroll
                for (int c = 0; c < 4; ++c)
                    acc[r][c] = fmaf(a[r], b[c], acc[r][c]);
        }
        __syncthreads();
    }
    float* dst = PX + ((size_t)(kz * 2 + srcT) * 128 + mt * 64) * N_DIM;
    #pragma unroll
    for (int r = 0; r < 4; ++r) {
        float4 o = make_float4(acc[r][0], acc[r][1], acc[r][2], acc[r][3]);
        *(float4*)&dst[(size_t)(ty * 4 + r) * N_DIM + n0 + tx * 4] = o;
    }
}

// ---------------------------------------------------------------------------
// Reduce PX partials, apply mask/bias/scale per use-case, split hi/lo bf16x3,
// write QF0/KF0/QF1/KF1 in score-fragment layout [256][6][64][8].
//   Q cat = [hi|hi|lo], K cat = [hi|lo|hi] over kstep pairs.
// ---------------------------------------------------------------------------
__global__ __launch_bounds__(256) void qkfinish(
    const float* __restrict__ PX,
    const float* __restrict__ s_m, const float* __restrict__ q_m,
    const float* __restrict__ bq, const float* __restrict__ bk,
    ushort* __restrict__ QF0, ushort* __restrict__ KF0,
    ushort* __restrict__ QF1, ushort* __restrict__ KF1)
{
    int gid = blockIdx.x * 256 + threadIdx.x;
    int lane = gid & 63;
    int rest = gid >> 6;
    int blk = rest & 255;
    int tensor = rest >> 8;       // 0..3
    int fr = lane & 15, quad = lane >> 4;
    int n = blk * 16 + fr;

    int srcT, rowbase, isQ;
    const float* bias;
    ushort* dst;
    float mv, scale;
    if (tensor == 0)      { srcT = 0; rowbase = 0;  isQ = 1; bias = bq; dst = QF0; scale = 0.125f; mv = s_m[n]; }
    else if (tensor == 1) { srcT = 1; rowbase = 64; isQ = 0; bias = bk; dst = KF0; scale = 1.0f;   mv = (q_m[n] > 0.8f) ? 1.0f : 0.0f; }
    else if (tensor == 2) { srcT = 1; rowbase = 0;  isQ = 1; bias = bq; dst = QF1; scale = 0.125f; mv = (q_m[n] > 0.8f) ? 1.0f : 0.0f; }
    else                  { srcT = 0; rowbase = 64; isQ = 0; bias = bk; dst = KF1; scale = 1.0f;   mv = 1.0f; }

    ushort hi0[8], lo0[8], hi1[8], lo1[8];
    #pragma unroll
    for (int j = 0; j < 8; ++j) {
        int d0 = quad * 8 + j, d1 = 32 + d0;
        float v0 = 0.0f, v1 = 0.0f;
        #pragma unroll
        for (int kz = 0; kz < 4; ++kz) {
            size_t base = ((size_t)(kz * 2 + srcT) * 128 + rowbase);
            v0 += PX[(base + d0) * N_DIM + n];
            v1 += PX[(base + d1) * N_DIM + n];
        }
        v0 = (v0 * mv + bias[d0]) * scale;
        v1 = (v1 * mv + bias[d1]) * scale;
        hi0[j] = f2bf(v0); lo0[j] = f2bf(v0 - bf2f(hi0[j]));
        hi1[j] = f2bf(v1); lo1[j] = f2bf(v1 - bf2f(hi1[j]));
    }
    auto wr8 = [&](int kstep, const ushort* v) {
        size_t base = ((size_t)(blk * 6 + kstep) * 64 + lane) * 8;
        *(ushort4*)&dst[base]     = *(const ushort4*)&v[0];
        *(ushort4*)&dst[base + 4] = *(const ushort4*)&v[4];
    };
    wr8(0, hi0); wr8(1, hi1);
    if (isQ) { wr8(2, hi0); wr8(3, hi1); wr8(4, lo0); wr8(5, lo1); }
    else     { wr8(2, lo0); wr8(3, lo1); wr8(4, hi0); wr8(5, hi1); }
}

// shared MFMA core for the two score passes (identical arithmetic order!)
__device__ __forceinline__ void scores_mfma(
    const ushort* __restrict__ QF, const ushort* __restrict__ KF,
    int m0, int n0, int wr, int wc, int lane, f32x4 acc[4][4])
{
    const int blkA0 = (m0 + wr) >> 4;
    const int blkB0 = (n0 + wc) >> 4;
    #pragma unroll
    for (int s = 0; s < 6; ++s) {
        short8 af[4], bf[4];
        #pragma unroll
        for (int mr = 0; mr < 4; ++mr)
            af[mr] = *(const short8*)&QF[((size_t)((blkA0 + mr) * 6 + s) * 64 + lane) * 8];
        #pragma unroll
        for (int nc = 0; nc < 4; ++nc)
            bf[nc] = *(const short8*)&KF[((size_t)((blkB0 + nc) * 6 + s) * 64 + lane) * 8];
        #pragma unroll
        for (int mr = 0; mr < 4; ++mr)
            #pragma unroll
            for (int nc = 0; nc < 4; ++nc)
                acc[mr][nc] = __builtin_amdgcn_mfma_f32_16x16x32_bf16(
                    af[mr], bf[nc], acc[mr][nc], 0, 0, 0);
    }
}

// pass 1 (z-batched): global max/min/sum partials + per-row max partials
__global__ __launch_bounds__(256) void scores_pass1(
    const ushort* __restrict__ QF0, const ushort* __restrict__ KF0,
    const ushort* __restrict__ QF1, const ushort* __restrict__ KF1,
    float* __restrict__ part, float* __restrict__ rowmaxp)
{
    const int br = blockIdx.z;
    const ushort* QF = br ? QF1 : QF0;
    const ushort* KF = br ? KF1 : KF0;
    part    += (size_t)br * 3072;
    rowmaxp += (size_t)br * 131072;

    const int lane = threadIdx.x & 63, wid = threadIdx.x >> 6;
    const int m0 = blockIdx.y * 128, n0 = blockIdx.x * 128;
    const int wr = (wid >> 1) * 64, wc = (wid & 1) * 64;
    f32x4 acc[4][4] = {};
    scores_mfma(QF, KF, m0, n0, wr, wc, lane, acc);

    float lmax = -3.4e38f, lmin = 3.4e38f, lsum = 0.0f;
    float rmx[4][4];
    #pragma unroll
    for (int mr = 0; mr < 4; ++mr)
        #pragma unroll
        for (int j = 0; j < 4; ++j) rmx[mr][j] = -3.4e38f;
    #pragma unroll
    for (int mr = 0; mr < 4; ++mr)
        #pragma unroll
        for (int nc = 0; nc < 4; ++nc)
            #pragma unroll
            for (int j = 0; j < 4; ++j) {
                float v = acc[mr][nc][j];
                lsum += v; lmax = fmaxf(lmax, v); lmin = fminf(lmin, v);
                rmx[mr][j] = fmaxf(rmx[mr][j], v);
            }
    #pragma unroll
    for (int m = 1; m < 16; m <<= 1)
        #pragma unroll
        for (int mr = 0; mr < 4; ++mr)
            #pragma unroll
            for (int j = 0; j < 4; ++j)
                rmx[mr][j] = fmaxf(rmx[mr][j], __shfl_xor(rmx[mr][j], m, 64));

    __shared__ float wrm[2][128];
    const int orow = (lane >> 4) * 4;
    if ((lane & 15) == 0) {
        #pragma unroll
        for (int mr = 0; mr < 4; ++mr)
            #pragma unroll
            for (int j = 0; j < 4; ++j)
                wrm[wid & 1][wr + mr * 16 + orow + j] = rmx[mr][j];
    }
    __syncthreads();
    if (threadIdx.x < 128) {
        float v = fmaxf(wrm[0][threadIdx.x], wrm[1][threadIdx.x]);
        rowmaxp[(size_t)blockIdx.x * 4096 + m0 + threadIdx.x] = v;
    }

    __shared__ float red[256];
    const int tid = threadIdx.x;
    const int bid = blockIdx.y * 32 + blockIdx.x;
    __syncthreads();
    red[tid] = lmax; __syncthreads();
    for (int s = 128; s > 0; s >>= 1) { if (tid < s) red[tid] = fmaxf(red[tid], red[tid + s]); __syncthreads(); }
    if (tid == 0) part[bid] = red[0];
    __syncthreads();
    red[tid] = lmin; __syncthreads();
    for (int s = 128; s > 0; s >>= 1) { if (tid < s) red[tid] = fminf(red[tid], red[tid + s]); __syncthreads(); }
    if (tid == 0) part[1024 + bid] = red[0];
    __syncthreads();
    red[tid] = lsum; __syncthreads();
    for (int s = 128; s > 0; s >>= 1) { if (tid < s) red[tid] += red[tid + s]; __syncthreads(); }
    if (tid == 0) part[2048 + bid] = red[0];
}

// thr per branch: branch0 max-based, branch1 min-based
__global__ __launch_bounds__(256) void stats_fin2(
    const float* __restrict__ part, float* __restrict__ stats)
{
    const int br = blockIdx.x;
    part += (size_t)br * 3072;
    __shared__ float rmax[256], rmin[256];
    __shared__ double rsum[256];
    int tid = threadIdx.x;
    float m1 = -3.4e38f, m2 = 3.4e38f; double s = 0.0;
    for (int i = tid; i < 1024; i += 256) {
        m1 = fmaxf(m1, part[i]);
        m2 = fminf(m2, part[1024 + i]);
        s += (double)part[2048 + i];
    }
    rmax[tid] = m1; rmin[tid] = m2; rsum[tid] = s;
    __syncthreads();
    for (int st = 128; st > 0; st >>= 1) {
        if (tid < st) {
            rmax[tid] = fmaxf(rmax[tid], rmax[tid + st]);
            rmin[tid] = fminf(rmin[tid], rmin[tid + st]);
            rsum[tid] += rsum[tid + st];
        }
        __syncthreads();
    }
    if (tid == 0) {
        float stat = (br == 0) ? rmax[0] : rmin[0];
        float mean = (float)(rsum[0] / (double)NN_TOT);
        stats[br] = 0.5f * (stat + mean);
    }
}

__global__ __launch_bounds__(256) void row_fin(
    const float* __restrict__ rowmaxp, const float* __restrict__ stats,
    float* __restrict__ rowm)
{
    const int br = blockIdx.y;
    int r = blockIdx.x * 256 + threadIdx.x;
    float thr = stats[br];
    float m = -3.4e38f;
    #pragma unroll 8
    for (int b = 0; b < 32; ++b)
        m = fmaxf(m, rowmaxp[(size_t)br * 131072 + (size_t)b * 4096 + r]);
    rowm[br * 4096 + r] = (m >= thr) ? m : -1e30f;
}

// pass 2 (z-batched): recompute scores, write e = exp(s-m) bf16 + rowsum partials
__global__ __launch_bounds__(256) void scores_pass2(
    const ushort* __restrict__ QF0, const ushort* __restrict__ KF0,
    const ushort* __restrict__ QF1, const ushort* __restrict__ KF1,
    const float* __restrict__ stats, const float* __restrict__ rowm,
    ushort* __restrict__ Pe, float* __restrict__ rowsump)
{
    const int br = blockIdx.z;
    const ushort* QF = br ? QF1 : QF0;
    const ushort* KF = br ? KF1 : KF0;
    ushort* P = Pe + (size_t)br * NN;
    rowsump += (size_t)br * 131072;
    rowm    += (size_t)br * 4096;

    const int lane = threadIdx.x & 63, wid = threadIdx.x >> 6;
    const int m0 = blockIdx.y * 128, n0 = blockIdx.x * 128;
    const int wr = (wid >> 1) * 64, wc = (wid & 1) * 64;
    f32x4 acc[4][4] = {};
    scores_mfma(QF, KF, m0, n0, wr, wc, lane, acc);

    const float thr = stats[br];
    const int orow = (lane >> 4) * 4;
    const int ocol = lane & 15;
    float rm[4][4], rs[4][4];
    #pragma unroll
    for (int mr = 0; mr < 4; ++mr)
        #pragma unroll
        for (int j = 0; j < 4; ++j) {
            rm[mr][j] = rowm[m0 + wr + mr * 16 + orow + j];
            rs[mr][j] = 0.0f;
        }
    #pragma unroll
    for (int mr = 0; mr < 4; ++mr)
        #pragma unroll
        for (int nc = 0; nc < 4; ++nc)
            #pragma unroll
            for (int j = 0; j < 4; ++j) {
                float s = acc[mr][nc][j];
                float m = rm[mr][j];
                float e = (s < thr) ? 0.0f : __expf(s - m);
                if (m < -1e29f) e = 1.0f;          // fully-masked row -> uniform
                ushort h = f2bf(e);
                rs[mr][j] += bf2f(h);
                P[(size_t)(m0 + wr + mr * 16 + orow + j) * N_DIM
                  + n0 + wc + nc * 16 + ocol] = h;
            }
    #pragma unroll
    for (int m = 1; m < 16; m <<= 1)
        #pragma unroll
        for (int mr = 0; mr < 4; ++mr)
            #pragma unroll
            for (int j = 0; j < 4; ++j)
                rs[mr][j] += __shfl_xor(rs[mr][j], m, 64);

    __shared__ float wrs[2][128];
    if ((lane & 15) == 0) {
        #pragma unroll
        for (int mr = 0; mr < 4; ++mr)
            #pragma unroll
            for (int j = 0; j < 4; ++j)
                wrs[wid & 1][wr + mr * 16 + orow + j] = rs[mr][j];
    }
    __syncthreads();
    if (threadIdx.x < 128)
        rowsump[(size_t)blockIdx.x * 4096 + m0 + threadIdx.x] =
            wrs[0][threadIdx.x] + wrs[1][threadIdx.x];
}

__global__ __launch_bounds__(256) void rsum_fin(
    const float* __restrict__ rowsump, float* __restrict__ invr)
{
    const int br = blockIdx.y;
    int r = blockIdx.x * 256 + threadIdx.x;
    float s = 0.0f;
    #pragma unroll 8
    for (int b = 0; b < 32; ++b)
        s += rowsump[(size_t)br * 131072 + (size_t)b * 4096 + r];
    invr[br * 4096 + r] = 1.0f / s;
}

// sum 2 split-K partials * per-row softmax scale -> bf16 (z-batched)
__global__ __launch_bounds__(256) void reduce2row(
    const float* __restrict__ P4, const float* __restrict__ invr,
    ushort* __restrict__ O)
{
    const int br = blockIdx.y;
    int i = (blockIdx.x * 256 + threadIdx.x) * 4;
    int row = i >> 9;                    // [4096][512]
    float sc = invr[br * 4096 + row];
    float4 a = *(const float4*)&P4[(size_t)(br * 2 + 0) * SZO + i];
    float4 b = *(const float4*)&P4[(size_t)(br * 2 + 1) * SZO + i];
    ushort4 o;
    o.x = f2bf((a.x + b.x) * sc);
    o.y = f2bf((a.y + b.y) * sc);
    o.z = f2bf((a.z + b.z) * sc);
    o.w = f2bf((a.w + b.w) * sc);
    *(ushort4*)&O[(size_t)br * SZO + i] = o;
}

// ---------------------------------------------------------------------------
__global__ __launch_bounds__(256) void ln_partial(
    const float* __restrict__ H2, float* __restrict__ lnp)
{
    const int br = blockIdx.y;
    const float* X = H2 + (size_t)br * CN;
    float* part = lnp + (size_t)br * 2048;
    __shared__ float rs[256], rq[256];
    int tid = threadIdx.x;
    size_t base = (size_t)blockIdx.x * 2048;
    float s = 0.0f, q = 0.0f;
    #pragma unroll
    for (int k = 0; k < 8; ++k) {
        float v = X[base + tid + k * 256];
        s += v; q = fmaf(v, v, q);
    }
    rs[tid] = s; rq[tid] = q; __syncthreads();
    for (int st = 128; st > 0; st >>= 1) {
        if (tid < st) { rs[tid] += rs[tid + st]; rq[tid] += rq[tid + st]; }
        __syncthreads();
    }
    if (tid == 0) { part[blockIdx.x] = rs[0]; part[1024 + blockIdx.x] = rq[0]; }
}

__global__ __launch_bounds__(256) void ln_fin(
    const float* __restrict__ lnp, float* __restrict__ stats)
{
    const int br = blockIdx.x;
    const float* part = lnp + (size_t)br * 2048;
    __shared__ double rs[256], rq[256];
    int tid = threadIdx.x;
    double s = 0.0, q = 0.0;
    for (int i = tid; i < 1024; i += 256) { s += part[i]; q += part[1024 + i]; }
    rs[tid] = s; rq[tid] = q; __syncthreads();
    for (int st = 128; st > 0; st >>= 1) {
        if (tid < st) { rs[tid] += rs[tid + st]; rq[tid] += rq[tid + st]; }
        __syncthreads();
    }
    if (tid == 0) {
        double mu = rs[0] / (double)CN;
        double var = rq[0] / (double)CN - mu * mu;
        stats[4 + 2 * br] = (float)mu;
        stats[5 + 2 * br] = (float)(1.0 / sqrt(var + 1e-5));
    }
}

__global__ __launch_bounds__(256) void gate_write(
    const float* __restrict__ H2, const float* __restrict__ stats,
    const float* __restrict__ gamma, const float* __restrict__ beta,
    const float* __restrict__ x, const float* __restrict__ y,
    const float* __restrict__ s_m, const float* __restrict__ q_m,
    float* __restrict__ out)
{
    const int br = blockIdx.y;
    size_t idx = (size_t)blockIdx.x * 256 + threadIdx.x;
    int n = (int)(idx & (N_DIM - 1));
    float mu = stats[4 + 2 * br], rstd = stats[5 + 2 * br];
    float normed = (H2[(size_t)br * CN + idx] - mu) * rstd * gamma[idx] + beta[idx];
    float mv = br ? ((q_m[n] > 0.8f) ? 1.0f : 0.0f) : s_m[n];
    const float* resid = br ? y : x;
    out[(size_t)br * CN + idx] = normed * mv + resid[idx] * (1.0f - mv);
}

// ---------------------------------------------------------------------------
extern "C" void kernel_launch(void* const* d_in, const int* in_sizes, int n_in,
                              void* d_out, int out_size, void* d_ws, size_t ws_size,
                              hipStream_t stream)
{
    const float* x     = (const float*)d_in[0];
    const float* y     = (const float*)d_in[1];
    const float* s_m   = (const float*)d_in[2];
    const float* q_m   = (const float*)d_in[3];
    const float* Wq    = (const float*)d_in[4];
    const float* bq    = (const float*)d_in[5];
    const float* Wk    = (const float*)d_in[6];
    const float* bk    = (const float*)d_in[7];
    const float* Wv    = (const float*)d_in[8];
    const float* bv    = (const float*)d_in[9];
    const float* W1    = (const float*)d_in[10];
    const float* b1    = (const float*)d_in[11];
    const float* W2    = (const float*)d_in[12];
    const float* b2    = (const float*)d_in[13];
    const float* gamma = (const float*)d_in[14];
    const float* beta  = (const float*)d_in[15];
    float* out = (float*)d_out;

    // ---- workspace layout (aliased; ~113 MB) ----
    float* ws = (float*)d_ws;
    float*  R1    = ws;                         // 8,388,608 f
    float*  PX    = R1;                         // [4][2][128][4096] (first 4,194,304 f)
    float*  P4    = R1;                         // [4][4096][512] split-K partials (all 8,388,608 f)
    ushort* QF0   = (ushort*)(R1 + 4194304);    // 4 x 786,432 us (upper half of R1; dead before P4 written)
    ushort* KF0   = QF0 + 786432;
    ushort* QF1   = KF0 + 786432;
    ushort* KF1   = QF1 + 786432;
    float*  SMALL = R1 + 8388608;
    float*  PART  = SMALL;                      // [2][3072]
    float*  RMAXP = PART + 6144;                // [2][131072]
    float*  RSUMP = RMAXP + 262144;             // [2][131072]
    float*  ROWM  = RSUMP + 262144;             // [2][4096]
    float*  INVR  = ROWM + 8192;                // [2][4096]
    float*  LNP   = INVR + 8192;                // [2][2048]
    float*  STATS = LNP + 4096;                 // 64
    ushort* Wvb   = (ushort*)(STATS + 64);      // 262,144 each
    ushort* W1b   = Wvb + 262144;
    ushort* W2b   = W1b + 262144;
    ushort* Vb    = W2b + 262144;               // [2][512][4096] = 4,194,304 us
    ushort* R2    = Vb + 4194304;               // 33,554,432 us region
    ushort* xbT   = R2;                         // [4096][512] (dead after V-proj)
    ushort* ybT   = R2 + 2097152;
    ushort* Pe    = R2;                         // [2][4096][4096] (written at pass2)
    ushort* O1T   = R2;                         // [2][4096][512] (written after VP; Pe dead)
    ushort* H1T   = R2 + 4194304;               // [2][4096][512]
    float*  H2    = (float*)(R2 + 8388608);     // [2][512][4096] f32

    // ---- setup converts ----
    tconv64<<<dim3(64, 8, 2), 256, 0, stream>>>(x, y, xbT, ybT);
    cvtw3<<<dim3(256, 3), 256, 0, stream>>>(Wv, W1, W2, Wvb, W1b, W2b);

    // ---- Q/K projections (f32 split-K, all 4 at once) ----
    qkraw<<<dim3(64, 4, 4), 256, 0, stream>>>(Wq, Wk, x, y, PX);
    qkfinish<<<256, 256, 0, stream>>>(PX, s_m, q_m, bq, bk, QF0, KF0, QF1, KF1);

    // ---- V projections, both branches: Vb[br] = Wv . (masked src) + bv ----
    mfma_g<128, 128><<<dim3(32, 4, 2), 256, 0, stream>>>(
        Wvb, Wvb, ybT, xbT, Vb, (size_t)CN,
        512, 4096, 512, 512, 1, bv, 1, q_m, 2, nullptr, 0, 0, 1);

    // ---- scores: stats pass + exp pass (both branches batched) ----
    scores_pass1<<<dim3(32, 32, 2), 256, 0, stream>>>(QF0, KF0, QF1, KF1, PART, RMAXP);
    stats_fin2<<<2, 256, 0, stream>>>(PART, STATS);
    row_fin<<<dim3(16, 2), 256, 0, stream>>>(RMAXP, STATS, ROWM);
    scores_pass2<<<dim3(32, 32, 2), 256, 0, stream>>>(QF0, KF0, QF1, KF1, STATS, ROWM, Pe, RSUMP);
    rsum_fin<<<dim3(16, 2), 256, 0, stream>>>(RSUMP, INVR);

    // ---- O1T[br][i][c] = sum_j Pe[i][j] Vb[c][j]  (split-K x2, batched) ----
    mfma_g<128, 128><<<dim3(4, 32, 4), 256, 0, stream>>>(
        Pe, Pe + NN, Vb, Vb + CN, P4, 0,
        4096, 512, 4096, 2048, 2, nullptr, 0, nullptr, 0, nullptr, 0, 0, 0);
    reduce2row<<<dim3(2048, 2), 256, 0, stream>>>(P4, INVR, O1T);

    // ---- MLP1: H1T = relu(O1T . W1^T + b1) ----
    mfma_g<128, 64><<<dim3(8, 32, 2), 256, 0, stream>>>(
        O1T, O1T + SZO, W1b, W1b, H1T, (size_t)SZO,
        4096, 512, 512, 512, 1, b1, 2, nullptr, 0, nullptr, 0, 1, 1);

    // ---- MLP2: H2 = W2 . H1T^T + b2  -> f32 [512][4096] ----
    mfma_g<64, 128><<<dim3(32, 8, 2), 256, 0, stream>>>(
        W2b, W2b, H1T, H1T + SZO, H2, (size_t)CN,
        512, 4096, 512, 512, 1, b2, 1, nullptr, 0, nullptr, 0, 0, 0);

    // ---- LayerNorm + gate ----
    ln_partial<<<dim3(1024, 2), 256, 0, stream>>>(H2, LNP);
    ln_fin<<<2, 256, 0, stream>>>(LNP, STATS);
    gate_write<<<dim3(8192, 2), 256, 0, stream>>>(
        H2, STATS, gamma, beta, x, y, s_m, q_m, out);
}

// Round 5
// 240.521 us; speedup vs baseline: 5.3727x; 1.0272x over previous
//
#include <hip/hip_runtime.h>
#include <math.h>

#define C_DIM 512
#define N_DIM 4096
#define CN (C_DIM * N_DIM)
#define SZO (N_DIM * C_DIM)          // 2,097,152 (pixel x channel)
#define NN ((size_t)N_DIM * N_DIM)
#define NN_TOT ((long long)N_DIM * N_DIM)

typedef __attribute__((ext_vector_type(4))) float f32x4;
typedef __attribute__((ext_vector_type(8))) short short8;

__device__ __forceinline__ ushort f2bf(float f) {
    unsigned u = __float_as_uint(f);
    unsigned r = u + 0x7FFFu + ((u >> 16) & 1u);
    return (ushort)(r >> 16);
}
__device__ __forceinline__ float bf2f(ushort h) {
    return __uint_as_float((unsigned)h << 16);
}

__device__ __forceinline__ void gload16(const void* g, void* l) {
    __builtin_amdgcn_global_load_lds(
        (const __attribute__((address_space(1))) void*)g,
        (__attribute__((address_space(3))) void*)l, 16, 0, 0);
}

// ---------------------------------------------------------------------------
// Transpose + convert: X f32 [512][4096] -> XT bf16 [4096][512], batched x/y
// ---------------------------------------------------------------------------
__global__ __launch_bounds__(256) void tconv64(
    const float* __restrict__ x, const float* __restrict__ y,
    ushort* __restrict__ xbT, ushort* __restrict__ ybT)
{
    const float* X = blockIdx.z ? y : x;
    ushort* XT = blockIdx.z ? ybT : xbT;
    __shared__ float t[64][65];
    const int c0 = blockIdx.x * 64;   // pixel dim
    const int r0 = blockIdx.y * 64;   // channel dim
    const int ty = threadIdx.x >> 4, tx = threadIdx.x & 15;
    #pragma unroll
    for (int i = 0; i < 4; ++i) {
        int r = ty + i * 16;
        float4 v = *(const float4*)&X[(size_t)(r0 + r) * N_DIM + c0 + tx * 4];
        t[r][tx * 4 + 0] = v.x; t[r][tx * 4 + 1] = v.y;
        t[r][tx * 4 + 2] = v.z; t[r][tx * 4 + 3] = v.w;
    }
    __syncthreads();
    #pragma unroll
    for (int i = 0; i < 4; ++i) {
        int nn = ty + i * 16;
        ushort4 o;
        o.x = f2bf(t[tx * 4 + 0][nn]); o.y = f2bf(t[tx * 4 + 1][nn]);
        o.z = f2bf(t[tx * 4 + 2][nn]); o.w = f2bf(t[tx * 4 + 3][nn]);
        *(ushort4*)&XT[(size_t)(c0 + nn) * C_DIM + r0 + tx * 4] = o;
    }
}

// batched weight converts (Wv, W1, W2 all 512x512)
__global__ __launch_bounds__(256) void cvtw3(
    const float* __restrict__ Wv, const float* __restrict__ W1,
    const float* __restrict__ W2, ushort* __restrict__ Wvb,
    ushort* __restrict__ W1b, ushort* __restrict__ W2b)
{
    const float* in  = (blockIdx.y == 0) ? Wv : (blockIdx.y == 1) ? W1 : W2;
    ushort*      out = (blockIdx.y == 0) ? Wvb : (blockIdx.y == 1) ? W1b : W2b;
    int i = (blockIdx.x * 256 + threadIdx.x) * 4;
    float4 v = *(const float4*)&in[i];
    ushort4 o = { f2bf(v.x), f2bf(v.y), f2bf(v.z), f2bf(v.w) };
    *(ushort4*)&out[i] = o;
}

// ---------------------------------------------------------------------------
// Generic bf16 MFMA NT GEMM, tile BM x BN, BK=32, 4 waves, double-buffered
// LDS via global_load_lds with k-chunk XOR swizzle (kb ^= (row>>1)&3) applied
// on the GLOBAL source address; ds_read applies the same XOR. Fixes the
// 8-way bank conflict of the 64B-row [r][32] layout.
// Branch-batched: z = br*nkz + kz. nkz>1: f32 split-K partials. swapxy: m on x.
// lnp != nullptr (nkz==1 only): per-block sum/sumsq partials for LayerNorm.
// ---------------------------------------------------------------------------
template<int BM, int BN>
__global__ __launch_bounds__(256) void mfma_g(
    const ushort* __restrict__ A0, const ushort* __restrict__ A1,
    const ushort* __restrict__ B0, const ushort* __restrict__ B1,
    void* __restrict__ Out, size_t outBrStride,
    int M, int N, int K, int kLen, int nkz, int swapxy,
    const float* __restrict__ bias, int biasMode,   // 0 none, 1 per-row m, 2 per-col n
    const float* __restrict__ mask0, int mm0,
    const float* __restrict__ mask1, int mm1,       // per-col n mask
    int doRelu, int outBf16, float* __restrict__ lnp)
{
    constexpr int WAVES_M = BM / 64;
    constexpr int WAVES_N = 4 / WAVES_M;
    constexpr int WN = BN / WAVES_N;
    constexpr int FM = 4;            // 64/16
    constexpr int FN = WN / 16;
    constexpr int NCHUNK = (BM + BN) / 16;

    __shared__ ushort As[2][BM * 32];
    __shared__ ushort Bs[2][BN * 32];
    const int tid  = threadIdx.x;
    const int lane = tid & 63;
    const int wid  = tid >> 6;
    const int z  = blockIdx.z;
    const int br = z / nkz;
    const int kz = z % nkz;
    const ushort* A = br ? A1 : A0;
    const ushort* B = br ? B1 : B0;
    const float* mask = br ? mask1 : mask0;
    const int maskMode = br ? mm1 : mm0;

    const int bxm = swapxy ? blockIdx.x : blockIdx.y;
    const int bxn = swapxy ? blockIdx.y : blockIdx.x;
    const int m0 = bxm * BM, n0 = bxn * BN;
    const int wm = wid / WAVES_N, wn = wid % WAVES_N;
    const int wr = wm * 64, wc = wn * WN;
    const int kOff = kz * kLen;
    const int lrow = lane >> 2;       // row within 16-row chunk
    const int kbl  = lane & 3;        // k-chunk 0..3 (8 ushorts each)

    auto stage = [&](int buf, int t) {
        #pragma unroll
        for (int c = wid; c < NCHUNK; c += 4) {
            if (c < BM / 16) {
                int r = c * 16 + lrow;
                int kb = kbl ^ ((r >> 1) & 3);
                gload16(A + (size_t)(m0 + r) * K + kOff + t * 32 + kb * 8,
                        &As[buf][c * 512]);
            } else {
                int cb = c - BM / 16;
                int r = cb * 16 + lrow;
                int kb = kbl ^ ((r >> 1) & 3);
                gload16(B + (size_t)(n0 + r) * K + kOff + t * 32 + kb * 8,
                        &Bs[buf][cb * 512]);
            }
        }
    };

    f32x4 acc[FM][FN] = {};
    const int fr = lane & 15;
    const int kq = lane >> 4;         // wanted k-chunk
    const int nt = kLen / 32;

    stage(0, 0);
    asm volatile("s_waitcnt vmcnt(0)" ::: "memory");
    __syncthreads();
    int cur = 0;
    for (int t = 0; t < nt; ++t) {
        if (t + 1 < nt) stage(cur ^ 1, t + 1);
        short8 af[FM], bf[FN];
        #pragma unroll
        for (int mr = 0; mr < FM; ++mr) {
            int rA = wr + mr * 16 + fr;
            af[mr] = *(const short8*)&As[cur][rA * 32 + (kq ^ ((rA >> 1) & 3)) * 8];
        }
        #pragma unroll
        for (int nc = 0; nc < FN; ++nc) {
            int rB = wc + nc * 16 + fr;
            bf[nc] = *(const short8*)&Bs[cur][rB * 32 + (kq ^ ((rB >> 1) & 3)) * 8];
        }
        #pragma unroll
        for (int mr = 0; mr < FM; ++mr)
            #pragma unroll
            for (int nc = 0; nc < FN; ++nc)
                acc[mr][nc] = __builtin_amdgcn_mfma_f32_16x16x32_bf16(
                    af[mr], bf[nc], acc[mr][nc], 0, 0, 0);
        asm volatile("s_waitcnt vmcnt(0)" ::: "memory");
        __syncthreads();
        cur ^= 1;
    }

    const int orow = (lane >> 4) * 4;
    const int ocol = lane & 15;

    if (nkz > 1) {   // split-K: raw f32 partials
        float* Of = (float*)Out + (size_t)z * M * N;
        #pragma unroll
        for (int mr = 0; mr < FM; ++mr)
            #pragma unroll
            for (int nc = 0; nc < FN; ++nc)
                #pragma unroll
                for (int j = 0; j < 4; ++j) {
                    int gm = m0 + wr + mr * 16 + orow + j;
                    int gn = n0 + wc + nc * 16 + ocol;
                    Of[(size_t)gm * N + gn] = acc[mr][nc][j];
                }
        return;
    }

    float mcol[FN], bcol[FN];
    #pragma unroll
    for (int nc = 0; nc < FN; ++nc) {
        int gn = n0 + wc + nc * 16 + ocol;
        mcol[nc] = (maskMode == 0) ? 1.0f
                 : (maskMode == 1) ? mask[gn]
                                   : (mask[gn] > 0.8f ? 1.0f : 0.0f);
        bcol[nc] = (biasMode == 2) ? bias[gn] : 0.0f;
    }
    ushort* Obf = (ushort*)Out + (size_t)br * outBrStride;
    float*  Of  = (float*)Out + (size_t)br * outBrStride;
    float lsum = 0.0f, lsq = 0.0f;
    #pragma unroll
    for (int mr = 0; mr < FM; ++mr) {
        #pragma unroll
        for (int j = 0; j < 4; ++j) {
            int gm = m0 + wr + mr * 16 + orow + j;
            float brow = (biasMode == 1) ? bias[gm] : 0.0f;
            #pragma unroll
            for (int nc = 0; nc < FN; ++nc) {
                int gn = n0 + wc + nc * 16 + ocol;
                float v = acc[mr][nc][j] * mcol[nc] + brow + bcol[nc];
                if (doRelu) v = fmaxf(v, 0.0f);
                if (outBf16) Obf[(size_t)gm * N + gn] = f2bf(v);
                else         Of[(size_t)gm * N + gn] = v;
                lsum += v; lsq = fmaf(v, v, lsq);
            }
        }
    }
    if (lnp) {   // per-block LayerNorm partials
        __shared__ float redS[256], redQ[256];
        redS[tid] = lsum; redQ[tid] = lsq;
        __syncthreads();
        for (int s = 128; s > 0; s >>= 1) {
            if (tid < s) { redS[tid] += redS[tid + s]; redQ[tid] += redQ[tid + s]; }
            __syncthreads();
        }
        if (tid == 0) {
            int fb = blockIdx.y * gridDim.x + blockIdx.x;
            lnp[br * 512 + fb] = redS[0];
            lnp[br * 512 + 256 + fb] = redQ[0];
        }
    }
}

// ---------------------------------------------------------------------------
// Raw Q/K projections, f32 split-K x2: PX[kz][src][128][4096]
// rows 0-63 = Wq.X, 64-127 = Wk.X.  grid (64 ntile, 4 = src*2+mt, 2 kz)
// ---------------------------------------------------------------------------
__global__ __launch_bounds__(256) void qkraw(
    const float* __restrict__ Wq, const float* __restrict__ Wk,
    const float* __restrict__ x, const float* __restrict__ y,
    float* __restrict__ PX)
{
    const int mt   = blockIdx.y & 1;
    const int srcT = blockIdx.y >> 1;
    const int kz   = blockIdx.z;
    const float* W = mt ? Wk : Wq;
    const float* X = srcT ? y : x;

    __shared__ float As[16][65];
    __shared__ float Bs[16][65];
    const int tid = threadIdx.x;
    const int n0 = blockIdx.x * 64;
    const int ty = tid >> 4, tx = tid & 15;
    float acc[4][4] = {};
    const int kbase = kz * 256;

    for (int k0 = kbase; k0 < kbase + 256; k0 += 16) {
        {
            int mm = tid >> 2, kq = (tid & 3) * 4;
            const float4 w4 = *(const float4*)&W[(size_t)mm * 512 + k0 + kq];
            As[kq + 0][mm] = w4.x; As[kq + 1][mm] = w4.y;
            As[kq + 2][mm] = w4.z; As[kq + 3][mm] = w4.w;
        }
        {
            int kk = tid >> 4, nq = (tid & 15) * 4;
            *(float4*)&Bs[kk][nq] = *(const float4*)&X[(size_t)(k0 + kk) * N_DIM + n0 + nq];
        }
        __syncthreads();
        #pragma unroll
        for (int kk = 0; kk < 16; ++kk) {
            float a[4], b[4];
            #pragma unroll
            for (int r = 0; r < 4; ++r) a[r] = As[kk][ty * 4 + r];
            #pragma unroll
            for (int c = 0; c < 4; ++c) b[c] = Bs[kk][tx * 4 + c];
            #pragma unroll
            for (int r = 0; r < 4; ++r)
                #pragma unroll
                for (int c = 0; c < 4; ++c)
                    acc[r][c] = fmaf(a[r], b[c], acc[r][c]);
        }
        __syncthreads();
    }
    float* dst = PX + ((size_t)(kz * 2 + srcT) * 128 + mt * 64) * N_DIM;
    #pragma unroll
    for (int r = 0; r < 4; ++r) {
        float4 o = make_float4(acc[r][0], acc[r][1], acc[r][2], acc[r][3]);
        *(float4*)&dst[(size_t)(ty * 4 + r) * N_DIM + n0 + tx * 4] = o;
    }
}

// ---------------------------------------------------------------------------
// Reduce PX partials, apply mask/bias/scale per use-case, split hi/lo bf16x3,
// write QF0/KF0/QF1/KF1 in score-fragment layout [256][6][64][8].
//   Q cat = [hi|hi|lo], K cat = [hi|lo|hi] over kstep pairs.
// ---------------------------------------------------------------------------
__global__ __launch_bounds__(256) void qkfinish(
    const float* __restrict__ PX,
    const float* __restrict__ s_m, const float* __restrict__ q_m,
    const float* __restrict__ bq, const float* __restrict__ bk,
    ushort* __restrict__ QF0, ushort* __restrict__ KF0,
    ushort* __restrict__ QF1, ushort* __restrict__ KF1)
{
    int gid = blockIdx.x * 256 + threadIdx.x;
    int lane = gid & 63;
    int rest = gid >> 6;
    int blk = rest & 255;
    int tensor = rest >> 8;       // 0..3
    int fr = lane & 15, quad = lane >> 4;
    int n = blk * 16 + fr;

    int srcT, rowbase, isQ;
    const float* bias;
    ushort* dst;
    float mv, scale;
    if (tensor == 0)      { srcT = 0; rowbase = 0;  isQ = 1; bias = bq; dst = QF0; scale = 0.125f; mv = s_m[n]; }
    else if (tensor == 1) { srcT = 1; rowbase = 64; isQ = 0; bias = bk; dst = KF0; scale = 1.0f;   mv = (q_m[n] > 0.8f) ? 1.0f : 0.0f; }
    else if (tensor == 2) { srcT = 1; rowbase = 0;  isQ = 1; bias = bq; dst = QF1; scale = 0.125f; mv = (q_m[n] > 0.8f) ? 1.0f : 0.0f; }
    else                  { srcT = 0; rowbase = 64; isQ = 0; bias = bk; dst = KF1; scale = 1.0f;   mv = 1.0f; }

    ushort hi0[8], lo0[8], hi1[8], lo1[8];
    #pragma unroll
    for (int j = 0; j < 8; ++j) {
        int d0 = quad * 8 + j, d1 = 32 + d0;
        float v0 = 0.0f, v1 = 0.0f;
        #pragma unroll
        for (int kz = 0; kz < 2; ++kz) {
            size_t base = ((size_t)(kz * 2 + srcT) * 128 + rowbase);
            v0 += PX[(base + d0) * N_DIM + n];
            v1 += PX[(base + d1) * N_DIM + n];
        }
        v0 = (v0 * mv + bias[d0]) * scale;
        v1 = (v1 * mv + bias[d1]) * scale;
        hi0[j] = f2bf(v0); lo0[j] = f2bf(v0 - bf2f(hi0[j]));
        hi1[j] = f2bf(v1); lo1[j] = f2bf(v1 - bf2f(hi1[j]));
    }
    auto wr8 = [&](int kstep, const ushort* v) {
        size_t base = ((size_t)(blk * 6 + kstep) * 64 + lane) * 8;
        *(ushort4*)&dst[base]     = *(const ushort4*)&v[0];
        *(ushort4*)&dst[base + 4] = *(const ushort4*)&v[4];
    };
    wr8(0, hi0); wr8(1, hi1);
    if (isQ) { wr8(2, hi0); wr8(3, hi1); wr8(4, lo0); wr8(5, lo1); }
    else     { wr8(2, lo0); wr8(3, lo1); wr8(4, hi0); wr8(5, hi1); }
}

// shared MFMA core for the two score passes (identical arithmetic order!)
__device__ __forceinline__ void scores_mfma(
    const ushort* __restrict__ QF, const ushort* __restrict__ KF,
    int m0, int n0, int wr, int wc, int lane, f32x4 acc[4][4])
{
    const int blkA0 = (m0 + wr) >> 4;
    const int blkB0 = (n0 + wc) >> 4;
    #pragma unroll
    for (int s = 0; s < 6; ++s) {
        short8 af[4], bf[4];
        #pragma unroll
        for (int mr = 0; mr < 4; ++mr)
            af[mr] = *(const short8*)&QF[((size_t)((blkA0 + mr) * 6 + s) * 64 + lane) * 8];
        #pragma unroll
        for (int nc = 0; nc < 4; ++nc)
            bf[nc] = *(const short8*)&KF[((size_t)((blkB0 + nc) * 6 + s) * 64 + lane) * 8];
        #pragma unroll
        for (int mr = 0; mr < 4; ++mr)
            #pragma unroll
            for (int nc = 0; nc < 4; ++nc)
                acc[mr][nc] = __builtin_amdgcn_mfma_f32_16x16x32_bf16(
                    af[mr], bf[nc], acc[mr][nc], 0, 0, 0);
    }
}

// pass 1 (z-batched): global max/min/sum partials + per-row max partials
__global__ __launch_bounds__(256) void scores_pass1(
    const ushort* __restrict__ QF0, const ushort* __restrict__ KF0,
    const ushort* __restrict__ QF1, const ushort* __restrict__ KF1,
    float* __restrict__ part, float* __restrict__ rowmaxp)
{
    const int br = blockIdx.z;
    const ushort* QF = br ? QF1 : QF0;
    const ushort* KF = br ? KF1 : KF0;
    part    += (size_t)br * 3072;
    rowmaxp += (size_t)br * 131072;

    const int lane = threadIdx.x & 63, wid = threadIdx.x >> 6;
    const int m0 = blockIdx.y * 128, n0 = blockIdx.x * 128;
    const int wr = (wid >> 1) * 64, wc = (wid & 1) * 64;
    f32x4 acc[4][4] = {};
    scores_mfma(QF, KF, m0, n0, wr, wc, lane, acc);

    float lmax = -3.4e38f, lmin = 3.4e38f, lsum = 0.0f;
    float rmx[4][4];
    #pragma unroll
    for (int mr = 0; mr < 4; ++mr)
        #pragma unroll
        for (int j = 0; j < 4; ++j) rmx[mr][j] = -3.4e38f;
    #pragma unroll
    for (int mr = 0; mr < 4; ++mr)
        #pragma unroll
        for (int nc = 0; nc < 4; ++nc)
            #pragma unroll
            for (int j = 0; j < 4; ++j) {
                float v = acc[mr][nc][j];
                lsum += v; lmax = fmaxf(lmax, v); lmin = fminf(lmin, v);
                rmx[mr][j] = fmaxf(rmx[mr][j], v);
            }
    #pragma unroll
    for (int m = 1; m < 16; m <<= 1)
        #pragma unroll
        for (int mr = 0; mr < 4; ++mr)
            #pragma unroll
            for (int j = 0; j < 4; ++j)
                rmx[mr][j] = fmaxf(rmx[mr][j], __shfl_xor(rmx[mr][j], m, 64));

    __shared__ float wrm[2][128];
    const int orow = (lane >> 4) * 4;
    if ((lane & 15) == 0) {
        #pragma unroll
        for (int mr = 0; mr < 4; ++mr)
            #pragma unroll
            for (int j = 0; j < 4; ++j)
                wrm[wid & 1][wr + mr * 16 + orow + j] = rmx[mr][j];
    }
    __syncthreads();
    if (threadIdx.x < 128) {
        float v = fmaxf(wrm[0][threadIdx.x], wrm[1][threadIdx.x]);
        rowmaxp[(size_t)blockIdx.x * 4096 + m0 + threadIdx.x] = v;
    }

    __shared__ float red[256];
    const int tid = threadIdx.x;
    const int bid = blockIdx.y * 32 + blockIdx.x;
    __syncthreads();
    red[tid] = lmax; __syncthreads();
    for (int s = 128; s > 0; s >>= 1) { if (tid < s) red[tid] = fmaxf(red[tid], red[tid + s]); __syncthreads(); }
    if (tid == 0) part[bid] = red[0];
    __syncthreads();
    red[tid] = lmin; __syncthreads();
    for (int s = 128; s > 0; s >>= 1) { if (tid < s) red[tid] = fminf(red[tid], red[tid + s]); __syncthreads(); }
    if (tid == 0) part[1024 + bid] = red[0];
    __syncthreads();
    red[tid] = lsum; __syncthreads();
    for (int s = 128; s > 0; s >>= 1) { if (tid < s) red[tid] += red[tid + s]; __syncthreads(); }
    if (tid == 0) part[2048 + bid] = red[0];
}

// thr per branch: branch0 max-based, branch1 min-based
__global__ __launch_bounds__(256) void stats_fin2(
    const float* __restrict__ part, float* __restrict__ stats)
{
    const int br = blockIdx.x;
    part += (size_t)br * 3072;
    __shared__ float rmax[256], rmin[256];
    __shared__ double rsum[256];
    int tid = threadIdx.x;
    float m1 = -3.4e38f, m2 = 3.4e38f; double s = 0.0;
    for (int i = tid; i < 1024; i += 256) {
        m1 = fmaxf(m1, part[i]);
        m2 = fminf(m2, part[1024 + i]);
        s += (double)part[2048 + i];
    }
    rmax[tid] = m1; rmin[tid] = m2; rsum[tid] = s;
    __syncthreads();
    for (int st = 128; st > 0; st >>= 1) {
        if (tid < st) {
            rmax[tid] = fmaxf(rmax[tid], rmax[tid + st]);
            rmin[tid] = fminf(rmin[tid], rmin[tid + st]);
            rsum[tid] += rsum[tid + st];
        }
        __syncthreads();
    }
    if (tid == 0) {
        float stat = (br == 0) ? rmax[0] : rmin[0];
        float mean = (float)(rsum[0] / (double)NN_TOT);
        stats[br] = 0.5f * (stat + mean);
    }
}

__global__ __launch_bounds__(256) void row_fin(
    const float* __restrict__ rowmaxp, const float* __restrict__ stats,
    float* __restrict__ rowm)
{
    const int br = blockIdx.y;
    int r = blockIdx.x * 256 + threadIdx.x;
    float thr = stats[br];
    float m = -3.4e38f;
    #pragma unroll 8
    for (int b = 0; b < 32; ++b)
        m = fmaxf(m, rowmaxp[(size_t)br * 131072 + (size_t)b * 4096 + r]);
    rowm[br * 4096 + r] = (m >= thr) ? m : -1e30f;
}

// pass 2 (z-batched): recompute scores, write e = exp(s-m) bf16 + rowsum partials
__global__ __launch_bounds__(256) void scores_pass2(
    const ushort* __restrict__ QF0, const ushort* __restrict__ KF0,
    const ushort* __restrict__ QF1, const ushort* __restrict__ KF1,
    const float* __restrict__ stats, const float* __restrict__ rowm,
    ushort* __restrict__ Pe, float* __restrict__ rowsump)
{
    const int br = blockIdx.z;
    const ushort* QF = br ? QF1 : QF0;
    const ushort* KF = br ? KF1 : KF0;
    ushort* P = Pe + (size_t)br * NN;
    rowsump += (size_t)br * 131072;
    rowm    += (size_t)br * 4096;

    const int lane = threadIdx.x & 63, wid = threadIdx.x >> 6;
    const int m0 = blockIdx.y * 128, n0 = blockIdx.x * 128;
    const int wr = (wid >> 1) * 64, wc = (wid & 1) * 64;
    f32x4 acc[4][4] = {};
    scores_mfma(QF, KF, m0, n0, wr, wc, lane, acc);

    const float thr = stats[br];
    const int orow = (lane >> 4) * 4;
    const int ocol = lane & 15;
    float rm[4][4], rs[4][4];
    #pragma unroll
    for (int mr = 0; mr < 4; ++mr)
        #pragma unroll
        for (int j = 0; j < 4; ++j) {
            rm[mr][j] = rowm[m0 + wr + mr * 16 + orow + j];
            rs[mr][j] = 0.0f;
        }
    #pragma unroll
    for (int mr = 0; mr < 4; ++mr)
        #pragma unroll
        for (int nc = 0; nc < 4; ++nc)
            #pragma unroll
            for (int j = 0; j < 4; ++j) {
                float s = acc[mr][nc][j];
                float m = rm[mr][j];
                float e = (s < thr) ? 0.0f : __expf(s - m);
                if (m < -1e29f) e = 1.0f;          // fully-masked row -> uniform
                ushort h = f2bf(e);
                rs[mr][j] += bf2f(h);
                P[(size_t)(m0 + wr + mr * 16 + orow + j) * N_DIM
                  + n0 + wc + nc * 16 + ocol] = h;
            }
    #pragma unroll
    for (int m = 1; m < 16; m <<= 1)
        #pragma unroll
        for (int mr = 0; mr < 4; ++mr)
            #pragma unroll
            for (int j = 0; j < 4; ++j)
                rs[mr][j] += __shfl_xor(rs[mr][j], m, 64);

    __shared__ float wrs[2][128];
    if ((lane & 15) == 0) {
        #pragma unroll
        for (int mr = 0; mr < 4; ++mr)
            #pragma unroll
            for (int j = 0; j < 4; ++j)
                wrs[wid & 1][wr + mr * 16 + orow + j] = rs[mr][j];
    }
    __syncthreads();
    if (threadIdx.x < 128)
        rowsump[(size_t)blockIdx.x * 4096 + m0 + threadIdx.x] =
            wrs[0][threadIdx.x] + wrs[1][threadIdx.x];
}

__global__ __launch_bounds__(256) void rsum_fin(
    const float* __restrict__ rowsump, float* __restrict__ invr)
{
    const int br = blockIdx.y;
    int r = blockIdx.x * 256 + threadIdx.x;
    float s = 0.0f;
    #pragma unroll 8
    for (int b = 0; b < 32; ++b)
        s += rowsump[(size_t)br * 131072 + (size_t)b * 4096 + r];
    invr[br * 4096 + r] = 1.0f / s;
}

// sum 2 split-K partials * per-row softmax scale -> bf16 (z-batched)
__global__ __launch_bounds__(256) void reduce2row(
    const float* __restrict__ P4, const float* __restrict__ invr,
    ushort* __restrict__ O)
{
    const int br = blockIdx.y;
    int i = (blockIdx.x * 256 + threadIdx.x) * 4;
    int row = i >> 9;                    // [4096][512]
    float sc = invr[br * 4096 + row];
    float4 a = *(const float4*)&P4[(size_t)(br * 2 + 0) * SZO + i];
    float4 b = *(const float4*)&P4[(size_t)(br * 2 + 1) * SZO + i];
    ushort4 o;
    o.x = f2bf((a.x + b.x) * sc);
    o.y = f2bf((a.y + b.y) * sc);
    o.z = f2bf((a.z + b.z) * sc);
    o.w = f2bf((a.w + b.w) * sc);
    *(ushort4*)&O[(size_t)br * SZO + i] = o;
}

// ---------------------------------------------------------------------------
__global__ __launch_bounds__(256) void ln_fin(
    const float* __restrict__ lnp, float* __restrict__ stats)
{
    const int br = blockIdx.x;
    const float* part = lnp + (size_t)br * 512;
    __shared__ double rs[256], rq[256];
    int tid = threadIdx.x;
    rs[tid] = (double)part[tid];
    rq[tid] = (double)part[256 + tid];
    __syncthreads();
    for (int st = 128; st > 0; st >>= 1) {
        if (tid < st) { rs[tid] += rs[tid + st]; rq[tid] += rq[tid + st]; }
        __syncthreads();
    }
    if (tid == 0) {
        double mu = rs[0] / (double)CN;
        double var = rq[0] / (double)CN - mu * mu;
        stats[4 + 2 * br] = (float)mu;
        stats[5 + 2 * br] = (float)(1.0 / sqrt(var + 1e-5));
    }
}

__global__ __launch_bounds__(256) void gate_write(
    const float* __restrict__ H2, const float* __restrict__ stats,
    const float* __restrict__ gamma, const float* __restrict__ beta,
    const float* __restrict__ x, const float* __restrict__ y,
    const float* __restrict__ s_m, const float* __restrict__ q_m,
    float* __restrict__ out)
{
    const int br = blockIdx.y;
    size_t i = ((size_t)blockIdx.x * 256 + threadIdx.x) * 4;
    int n = (int)(i & (N_DIM - 1));
    float mu = stats[4 + 2 * br], rstd = stats[5 + 2 * br];
    float4 h = *(const float4*)&H2[(size_t)br * CN + i];
    float4 g = *(const float4*)&gamma[i];
    float4 b = *(const float4*)&beta[i];
    const float* resid = br ? y : x;
    float4 r = *(const float4*)&resid[i];
    float4 o;
    float vals[4] = { h.x, h.y, h.z, h.w };
    float gs[4] = { g.x, g.y, g.z, g.w };
    float bs[4] = { b.x, b.y, b.z, b.w };
    float rs[4] = { r.x, r.y, r.z, r.w };
    float os[4];
    #pragma unroll
    for (int j = 0; j < 4; ++j) {
        float mv = br ? ((q_m[n + j] > 0.8f) ? 1.0f : 0.0f) : s_m[n + j];
        float normed = (vals[j] - mu) * rstd * gs[j] + bs[j];
        os[j] = normed * mv + rs[j] * (1.0f - mv);
    }
    o.x = os[0]; o.y = os[1]; o.z = os[2]; o.w = os[3];
    *(float4*)&out[(size_t)br * CN + i] = o;
}

// ---------------------------------------------------------------------------
extern "C" void kernel_launch(void* const* d_in, const int* in_sizes, int n_in,
                              void* d_out, int out_size, void* d_ws, size_t ws_size,
                              hipStream_t stream)
{
    const float* x     = (const float*)d_in[0];
    const float* y     = (const float*)d_in[1];
    const float* s_m   = (const float*)d_in[2];
    const float* q_m   = (const float*)d_in[3];
    const float* Wq    = (const float*)d_in[4];
    const float* bq    = (const float*)d_in[5];
    const float* Wk    = (const float*)d_in[6];
    const float* bk    = (const float*)d_in[7];
    const float* Wv    = (const float*)d_in[8];
    const float* bv    = (const float*)d_in[9];
    const float* W1    = (const float*)d_in[10];
    const float* b1    = (const float*)d_in[11];
    const float* W2    = (const float*)d_in[12];
    const float* b2    = (const float*)d_in[13];
    const float* gamma = (const float*)d_in[14];
    const float* beta  = (const float*)d_in[15];
    float* out = (float*)d_out;

    // ---- workspace layout (aliased) ----
    float* ws = (float*)d_ws;
    float*  R1    = ws;                         // 8,388,608 f
    float*  PX    = R1;                         // [2][2][128][4096] (4,194,304 f)
    float*  P4    = R1;                         // [4][4096][512] split-K partials
    ushort* QF0   = (ushort*)(R1 + 4194304);    // 4 x 786,432 us (dead before P4)
    ushort* KF0   = QF0 + 786432;
    ushort* QF1   = KF0 + 786432;
    ushort* KF1   = QF1 + 786432;
    float*  SMALL = R1 + 8388608;
    float*  PART  = SMALL;                      // [2][3072]
    float*  RMAXP = PART + 6144;                // [2][131072]
    float*  RSUMP = RMAXP + 262144;             // [2][131072]
    float*  ROWM  = RSUMP + 262144;             // [2][4096]
    float*  INVR  = ROWM + 8192;                // [2][4096]
    float*  LNP   = INVR + 8192;                // [2][512]
    float*  STATS = LNP + 1024;                 // 64
    ushort* Wvb   = (ushort*)(STATS + 64);      // 262,144 each
    ushort* W1b   = Wvb + 262144;
    ushort* W2b   = W1b + 262144;
    ushort* Vb    = W2b + 262144;               // [2][512][4096]
    ushort* R2    = Vb + 4194304;               // big region
    ushort* xbT   = R2;                         // [4096][512] (dead after V-proj)
    ushort* ybT   = R2 + 2097152;
    ushort* Pe    = R2;                         // [2][4096][4096]
    ushort* O1T   = R2;                         // [2][4096][512] (Pe dead)
    ushort* H1T   = R2 + 4194304;               // [2][4096][512]
    float*  H2    = (float*)(R2 + 8388608);     // [2][512][4096] f32

    // ---- setup converts ----
    tconv64<<<dim3(64, 8, 2), 256, 0, stream>>>(x, y, xbT, ybT);
    cvtw3<<<dim3(256, 3), 256, 0, stream>>>(Wv, W1, W2, Wvb, W1b, W2b);

    // ---- Q/K projections (f32 split-K x2, all 4 at once) ----
    qkraw<<<dim3(64, 4, 2), 256, 0, stream>>>(Wq, Wk, x, y, PX);
    qkfinish<<<256, 256, 0, stream>>>(PX, s_m, q_m, bq, bk, QF0, KF0, QF1, KF1);

    // ---- V projections, both branches ----
    mfma_g<128, 128><<<dim3(32, 4, 2), 256, 0, stream>>>(
        Wvb, Wvb, ybT, xbT, Vb, (size_t)CN,
        512, 4096, 512, 512, 1, 0, bv, 1, q_m, 2, nullptr, 0, 0, 1, nullptr);

    // ---- scores: stats pass + exp pass ----
    scores_pass1<<<dim3(32, 32, 2), 256, 0, stream>>>(QF0, KF0, QF1, KF1, PART, RMAXP);
    stats_fin2<<<2, 256, 0, stream>>>(PART, STATS);
    row_fin<<<dim3(16, 2), 256, 0, stream>>>(RMAXP, STATS, ROWM);
    scores_pass2<<<dim3(32, 32, 2), 256, 0, stream>>>(QF0, KF0, QF1, KF1, STATS, ROWM, Pe, RSUMP);
    rsum_fin<<<dim3(16, 2), 256, 0, stream>>>(RSUMP, INVR);

    // ---- O1T[br][i][c] = sum_j Pe[i][j] Vb[c][j] (split-K x2, swapped axes
    //      so the 4 blocks sharing a Pe row-slab land on one XCD) ----
    mfma_g<128, 128><<<dim3(32, 4, 4), 256, 0, stream>>>(
        Pe, Pe + NN, Vb, Vb + CN, P4, 0,
        4096, 512, 4096, 2048, 2, 1, nullptr, 0, nullptr, 0, nullptr, 0, 0, 0, nullptr);
    reduce2row<<<dim3(2048, 2), 256, 0, stream>>>(P4, INVR, O1T);

    // ---- MLP1: H1T = relu(O1T . W1^T + b1), swapped axes ----
    mfma_g<128, 64><<<dim3(32, 8, 2), 256, 0, stream>>>(
        O1T, O1T + SZO, W1b, W1b, H1T, (size_t)SZO,
        4096, 512, 512, 512, 1, 1, b1, 2, nullptr, 0, nullptr, 0, 1, 1, nullptr);

    // ---- MLP2: H2 = W2 . H1T^T + b2 -> f32, fused LN partials ----
    mfma_g<64, 128><<<dim3(32, 8, 2), 256, 0, stream>>>(
        W2b, W2b, H1T, H1T + SZO, H2, (size_t)CN,
        512, 4096, 512, 512, 1, 0, b2, 1, nullptr, 0, nullptr, 0, 0, 0, LNP);

    // ---- LayerNorm finalize + gate ----
    ln_fin<<<2, 256, 0, stream>>>(LNP, STATS);
    gate_write<<<dim3(2048, 2), 256, 0, stream>>>(
        H2, STATS, gamma, beta, x, y, s_m, q_m, out);
}